// Round 8
// baseline (352.448 us; speedup 1.0000x reference)
//
#include <hip/hip_runtime.h>
#include <hip/hip_bf16.h>
#include <math.h>

#define NB 4
#define NPTS 4096
#define DIM 256
#define KNN 16
#define HID 64
#define FFDIM 1024
#define LN_EPS 1e-5f
#define MTOT (NB * NPTS)
#define KINF 3e38f
#define QPB 8

typedef __attribute__((ext_vector_type(8))) short short8;
typedef __attribute__((ext_vector_type(4))) float f32x4;

__device__ __forceinline__ float gelu_f(float x) {
    return 0.5f * x * (1.0f + erff(x * 0.7071067811865476f));
}
__device__ __forceinline__ float b2f(ushort u) {
    return __uint_as_float(((unsigned)u) << 16);
}
__device__ __forceinline__ ushort f2b(float f) {
    unsigned u = __float_as_uint(f);
    return (ushort)((u + 0x7fffu + ((u >> 16) & 1u)) >> 16);
}
__device__ __forceinline__ void gload16(const void* g, void* l) {
    __builtin_amdgcn_global_load_lds((const __attribute__((address_space(1))) void*)g,
                                     (__attribute__((address_space(3))) void*)l, 16, 0, 0);
}
// dot of 8 bf16 (packed in uint4) with 8 consecutive f32
__device__ __forceinline__ float dot8(uint4 w, const float* q) {
    float s = 0.f;
    s += b2f((ushort)(w.x & 0xffff)) * q[0]; s += b2f((ushort)(w.x >> 16)) * q[1];
    s += b2f((ushort)(w.y & 0xffff)) * q[2]; s += b2f((ushort)(w.y >> 16)) * q[3];
    s += b2f((ushort)(w.z & 0xffff)) * q[4]; s += b2f((ushort)(w.z >> 16)) * q[5];
    s += b2f((ushort)(w.w & 0xffff)) * q[6]; s += b2f((ushort)(w.w >> 16)) * q[7];
    return s;
}

// ---------------------------------------------------------------------------
// KNN v5: 8 queries per block; per-thread 16 points + |p|^2 cached in regs.
// Per query: lane-min -> per-wave bitonic value sort-64 -> T_w = lane15;
// T = min_w T_w (>=16 candidates guaranteed by the min-achieving wave);
// compact d<=T (cap 64). After loop: wave w lexicographically sorts queries
// w and w+4 (parallel across waves), lanes 0..15 write.
// ---------------------------------------------------------------------------
__global__ __launch_bounds__(256) void knn_kernel(const float* __restrict__ xyz,
                                                  int* __restrict__ idx_out) {
    int blk = blockIdx.x;              // 0..MTOT/QPB-1
    int bq0 = blk * QPB;
    int b = bq0 >> 12;                 // same batch for all 8 (QPB | NPTS)
    const float* base = xyz + (size_t)b * NPTS * 3;
    int t = threadIdx.x;
    int lane = t & 63, wv = t >> 6;

    __shared__ float TwS[4];
    __shared__ int   cnt[QPB];
    __shared__ float cV[QPB][64];
    __shared__ int   cI[QPB][64];

    if (t < QPB) cnt[t] = 0;

    float px[16], py[16], pz[16], sq[16];
    #pragma unroll
    for (int i = 0; i < 16; ++i) {
        int m = t + 256 * i;
        px[i] = base[m * 3 + 0];
        py[i] = base[m * 3 + 1];
        pz[i] = base[m * 3 + 2];
        sq[i] = px[i] * px[i] + py[i] * py[i] + pz[i] * pz[i];
    }
    __syncthreads();

    #pragma unroll 1
    for (int qi = 0; qi < QPB; ++qi) {
        int bn = bq0 + qi;
        int n = bn & (NPTS - 1);
        float qx = base[n * 3 + 0], qy = base[n * 3 + 1], qz = base[n * 3 + 2];
        float sqn = qx * qx + qy * qy + qz * qz;

        float d[16];
        #pragma unroll
        for (int i = 0; i < 16; ++i) {
            int m = t + 256 * i;
            float dot = px[i] * qx + py[i] * qy + pz[i] * qz;
            float dd = (sqn + sq[i]) - 2.0f * dot;
            d[i] = (m == n) ? KINF : dd;
        }
        float lmin = d[0];
        #pragma unroll
        for (int i = 1; i < 16; ++i) lmin = fminf(lmin, d[i]);

        // per-wave ascending bitonic value sort of 64 lane-mins
        float v = lmin;
        #pragma unroll
        for (int k = 2; k <= 64; k <<= 1) {
            #pragma unroll
            for (int j = 32; j > 0; j >>= 1) {
                if (j < k) {
                    float ov = __shfl_xor(v, j, 64);
                    bool keepMin = ((lane & k) == 0) == ((lane & j) == 0);
                    if (keepMin == (ov < v)) v = ov;
                }
            }
        }
        if (lane == 15) TwS[wv] = v;   // wave's 16th-smallest lane-min
        __syncthreads();

        float T = fminf(fminf(TwS[0], TwS[1]), fminf(TwS[2], TwS[3]));
        #pragma unroll
        for (int i = 0; i < 16; ++i) {
            if (d[i] <= T) {
                int pos = atomicAdd(&cnt[qi], 1);
                if (pos < 64) { cV[qi][pos] = d[i]; cI[qi][pos] = t + 256 * i; }
            }
        }
        __syncthreads();   // cnt/cV final; TwS safe to overwrite next qi
    }

    // final: wave w sorts queries w and w+4 (lexicographic (d, idx), 64-wide)
    #pragma unroll
    for (int rep = 0; rep < 2; ++rep) {
        int qi = wv + 4 * rep;
        int nc = cnt[qi]; nc = nc > 64 ? 64 : nc;
        float v = (lane < nc) ? cV[qi][lane] : KINF;
        int   m = (lane < nc) ? cI[qi][lane] : 0x7fffffff;
        #pragma unroll
        for (int k = 2; k <= 64; k <<= 1) {
            #pragma unroll
            for (int j = 32; j > 0; j >>= 1) {
                if (j < k) {
                    float ov = __shfl_xor(v, j, 64);
                    int   om = __shfl_xor(m, j, 64);
                    bool keepMin = ((lane & k) == 0) == ((lane & j) == 0);
                    bool less = (ov < v) || (ov == v && om < m);
                    if (keepMin == less) { v = ov; m = om; }
                }
            }
        }
        if (lane < KNN) idx_out[(size_t)(bq0 + qi) * KNN + lane] = m;
    }
}

// ---------------------------------------------------------------------------
// LayerNorm f32 in -> bf16 out
// ---------------------------------------------------------------------------
__global__ __launch_bounds__(256) void ln_kernel(const float* __restrict__ in,
                                                 const float* __restrict__ g,
                                                 const float* __restrict__ bb,
                                                 ushort* __restrict__ out) {
    int r = blockIdx.x;
    int t = threadIdx.x;
    float v = in[(size_t)r * DIM + t];

    __shared__ float sw[4];
    __shared__ float sw2[4];

    float s = v;
    #pragma unroll
    for (int off = 32; off > 0; off >>= 1) s += __shfl_down(s, off);
    if ((t & 63) == 0) sw[t >> 6] = s;
    __syncthreads();
    float mean = (sw[0] + sw[1] + sw[2] + sw[3]) * (1.0f / DIM);

    float dlt = v - mean;
    float s2 = dlt * dlt;
    #pragma unroll
    for (int off = 32; off > 0; off >>= 1) s2 += __shfl_down(s2, off);
    if ((t & 63) == 0) sw2[t >> 6] = s2;
    __syncthreads();
    float var = (sw2[0] + sw2[1] + sw2[2] + sw2[3]) * (1.0f / DIM);

    out[(size_t)r * DIM + t] = f2b(dlt * rsqrtf(var + LN_EPS) * g[t] + bb[t]);
}

// ---------------------------------------------------------------------------
// Transpose-convert: f32 in[R][C] -> bf16 out[C][R]
// ---------------------------------------------------------------------------
__global__ __launch_bounds__(256) void tconv(const float* __restrict__ in,
                                             ushort* __restrict__ out, int R, int C) {
    __shared__ float tile[32][33];
    int tx = threadIdx.x & 31, ty = threadIdx.x >> 5;
    int r0 = blockIdx.y * 32, c0 = blockIdx.x * 32;
    #pragma unroll
    for (int k = 0; k < 4; ++k)
        tile[ty + 8 * k][tx] = in[(size_t)(r0 + ty + 8 * k) * C + c0 + tx];
    __syncthreads();
    #pragma unroll
    for (int k = 0; k < 4; ++k)
        out[(size_t)(c0 + ty + 8 * k) * R + r0 + tx] = f2b(tile[tx][ty + 8 * k]);
}

// straight f32 -> bf16
__global__ __launch_bounds__(256) void conv_k(const float* __restrict__ in,
                                              ushort* __restrict__ out) {
    int i = blockIdx.x * 256 + threadIdx.x;
    out[i] = f2b(in[i]);
}

// w2bd[n][k] = (head(k)==head(n)) ? W_rel2[n&63][k] : 0   (bf16, [256][256])
__global__ __launch_bounds__(256) void w2bd_kernel(const float* __restrict__ W2,
                                                   ushort* __restrict__ out) {
    int n = blockIdx.x, k = threadIdx.x;
    float v = ((k >> 6) == (n >> 6)) ? W2[(n & 63) * 256 + k] : 0.0f;
    out[n * 256 + k] = f2b(v);
}

// bqw[n] = sum_{d in head(n)} bq[d] * W_rel2[n&63][d]   (one block)
__global__ __launch_bounds__(256) void bqw_kernel(const float* __restrict__ bq,
                                                  const float* __restrict__ W2,
                                                  float* __restrict__ out) {
    int n = threadIdx.x;
    int h = n >> 6, i = n & 63;
    float s = 0.f;
    #pragma unroll 8
    for (int dp = 0; dp < 64; ++dp) s += bq[h * 64 + dp] * W2[i * 256 + h * 64 + dp];
    out[n] = s;
}

// bocat[col] = bo[col] + sum_d b_rel2[d] * Wo[d][col]   (one block)
__global__ __launch_bounds__(256) void bocat_kernel(const float* __restrict__ bo,
                                                    const float* __restrict__ br2,
                                                    const float* __restrict__ Wo,
                                                    float* __restrict__ out) {
    int col = threadIdx.x;
    float s = bo[col];
    #pragma unroll 8
    for (int d = 0; d < 256; ++d) s += br2[d] * Wo[d * 256 + col];
    out[col] = s;
}

// BtCat[col][0:256] = WoT[col][:]
__global__ __launch_bounds__(256) void catL_kernel(const ushort* __restrict__ WoT,
                                                   ushort* __restrict__ BtCat) {
    int i = blockIdx.x * 256 + threadIdx.x;   // 65536
    BtCat[(size_t)(i >> 8) * 512 + (i & 255)] = WoT[i];
}

// ---------------------------------------------------------------------------
// MFMA bf16 GEMM: C[M][ldc] = act(A[M][K] @ Bt[N][K]^T + bias) (+res)
// ---------------------------------------------------------------------------
template <int ACT, int OUTBF, int RES>
__global__ __launch_bounds__(256) void gemm_bt(
    const ushort* __restrict__ A, const ushort* __restrict__ Bt,
    const float* __restrict__ bias, const float* __restrict__ res,
    void* __restrict__ Cv, int M, int N, int K, int ldc)
{
    __shared__ ushort As[4096];   // [128][32] bf16, swizzled
    __shared__ ushort Bs[4096];
    const int t = threadIdx.x;
    const int wave = t >> 6, lane = t & 63;
    const int m0 = blockIdx.y * 128, n0 = blockIdx.x * 128;
    const int wr = (wave >> 1) * 64, wc = (wave & 1) * 64;

    f32x4 acc[4][4];
    #pragma unroll
    for (int i = 0; i < 4; ++i)
        #pragma unroll
        for (int j = 0; j < 4; ++j) acc[i][j] = {0.f, 0.f, 0.f, 0.f};

    const int rA0 = (wave * 2 + 0) * 16 + (lane >> 2);
    const int rA1 = (wave * 2 + 1) * 16 + (lane >> 2);
    const int u4 = lane & 3;
    const int sw0 = (rA0 + (rA0 >> 2)) & 3;
    const int sw1 = (rA1 + (rA1 >> 2)) & 3;
    char* ldsA0 = (char*)As + (wave * 2 + 0) * 1024 + lane * 16;
    char* ldsA1 = (char*)As + (wave * 2 + 1) * 1024 + lane * 16;
    char* ldsB0 = (char*)Bs + (wave * 2 + 0) * 1024 + lane * 16;
    char* ldsB1 = (char*)Bs + (wave * 2 + 1) * 1024 + lane * 16;
    const size_t aOff0 = (size_t)(m0 + rA0) * K + (size_t)((u4 ^ sw0) * 8);
    const size_t aOff1 = (size_t)(m0 + rA1) * K + (size_t)((u4 ^ sw1) * 8);
    const size_t bOff0 = (size_t)(n0 + rA0) * K + (size_t)((u4 ^ sw0) * 8);
    const size_t bOff1 = (size_t)(n0 + rA1) * K + (size_t)((u4 ^ sw1) * 8);

    const int cl = lane & 15, gq = lane >> 4;

    for (int k0 = 0; k0 < K; k0 += 32) {
        gload16(A + aOff0 + k0, ldsA0);
        gload16(A + aOff1 + k0, ldsA1);
        gload16(Bt + bOff0 + k0, ldsB0);
        gload16(Bt + bOff1 + k0, ldsB1);
        __syncthreads();

        short8 av[4], bv[4];
        #pragma unroll
        for (int mi = 0; mi < 4; ++mi) {
            int row = wr + mi * 16 + cl;
            int s = (row + (row >> 2)) & 3;
            av[mi] = *(const short8*)((const char*)As + row * 64 + ((gq ^ s) << 4));
            int rowb = wc + mi * 16 + cl;
            int sb = (rowb + (rowb >> 2)) & 3;
            bv[mi] = *(const short8*)((const char*)Bs + rowb * 64 + ((gq ^ sb) << 4));
        }
        #pragma unroll
        for (int mi = 0; mi < 4; ++mi)
            #pragma unroll
            for (int ni = 0; ni < 4; ++ni)
                acc[mi][ni] = __builtin_amdgcn_mfma_f32_16x16x32_bf16(av[mi], bv[ni], acc[mi][ni], 0, 0, 0);
        __syncthreads();
    }

    float* Cf = (float*)Cv;
    ushort* Cb = (ushort*)Cv;
    #pragma unroll
    for (int ni = 0; ni < 4; ++ni) {
        int col = n0 + wc + ni * 16 + cl;
        float bvv = bias ? bias[col] : 0.0f;
        #pragma unroll
        for (int mi = 0; mi < 4; ++mi) {
            #pragma unroll
            for (int r = 0; r < 4; ++r) {
                int row = m0 + wr + mi * 16 + gq * 4 + r;
                float v = acc[mi][ni][r] + bvv;
                if (ACT == 1) v = gelu_f(v);
                if (RES) v += res[(size_t)row * N + col];
                if (OUTBF) Cb[(size_t)row * ldc + col] = f2b(v);
                else       Cf[(size_t)row * ldc + col] = v;
            }
        }
    }
}

// ---------------------------------------------------------------------------
// hid = gelu(rel @ W_rel1 + b_rel1) -> bf16
// ---------------------------------------------------------------------------
__global__ __launch_bounds__(256) void hid_kernel(const float* __restrict__ xyz,
                                                  const int* __restrict__ idx,
                                                  const float* __restrict__ W1,
                                                  const float* __restrict__ b1,
                                                  ushort* __restrict__ hid) {
    int t = threadIdx.x;
    int rl = t >> 6, i = t & 63;
    int row = blockIdx.x * 4 + rl;
    int bn = row >> 4;
    int b = bn >> 12;
    int n = bn & (NPTS - 1);
    int m = idx[row];
    const float* xb = xyz + (size_t)b * NPTS * 3;
    float dx = xb[m * 3 + 0] - xb[n * 3 + 0];
    float dy = xb[m * 3 + 1] - xb[n * 3 + 1];
    float dz = xb[m * 3 + 2] - xb[n * 3 + 2];
    float nr = sqrtf(dx * dx + dy * dy + dz * dz);
    float a = b1[i] + dx * W1[i] + dy * W1[64 + i] + dz * W1[128 + i] + nr * W1[192 + i];
    hid[(size_t)row * 64 + i] = f2b(gelu_f(a));
}

// ---------------------------------------------------------------------------
// Attention v2 (factored, W2 contractions hoisted to GEMMs):
//   logit_hj = ( q_h . k_j|h  +  qw_h . hid_j ) / 8
//   outputs: ab[bn][0:256]   = partial_d = sum_j p_j v_j[d]
//            ab[bn][256:512] = hp[(h,i)] = sum_j p_hj hid_j[i]
//   (ab right half holds qwg on entry; overwritten after staging)
// 8 points/block; wave == head; XCD-contiguous block swizzle.
// ---------------------------------------------------------------------------
#define PTS 8
__global__ __launch_bounds__(256) void attn_kernel(
    const int* __restrict__ idx,
    const ushort* __restrict__ qb, const ushort* __restrict__ kb,
    const ushort* __restrict__ vb, const ushort* __restrict__ hidg,
    ushort* __restrict__ ab)
{
    __shared__ float qS[256];
    __shared__ float qwS[256];
    __shared__ float psS[64];
    __shared__ uint4 hidS4[16 * 9];   // [16 rows][stride 144B], 8 valid chunks
    __shared__ int   nbAll[128];
    ushort* hidS = (ushort*)hidS4;

    const int t = threadIdx.x;
    const int h = t >> 6, lane = t & 63;
    const int bid = blockIdx.x;
    const int blk = ((bid & 7) << 8) | (bid >> 3);   // 2048 = 8*256, bijective
    const int bn0 = blk * PTS;
    const int R0 = blk * (PTS * 16);

    if (t < 128) nbAll[t] = idx[R0 + t];

    for (int pt = 0; pt < PTS; ++pt) {
        const int bn = bn0 + pt;
        const size_t base = (size_t)(bn >> 12) * NPTS;

        qS[t]  = b2f(qb[(size_t)bn * 256 + t]);
        qwS[t] = b2f(ab[(size_t)bn * 512 + 256 + t]);
        if (t < 128) {
            int j = t >> 3, c = t & 7;
            hidS4[j * 9 + c] = *(const uint4*)(hidg + (size_t)(R0 + pt * 16 + j) * 64 + c * 8);
        }
        __syncthreads();

        // logits + softmax (wave h = head h; lane = j*4+sub)
        {
            int j = lane >> 2, sub = lane & 3;
            int m = nbAll[pt * 16 + j];
            const ushort* krow = kb + (base + m) * 256 + h * 64 + sub * 16;
            uint4 ka = *(const uint4*)krow;
            uint4 kc = *(const uint4*)(krow + 8);
            const float* qp = &qS[h * 64 + sub * 16];
            float d1 = dot8(ka, qp) + dot8(kc, qp + 8);
            const ushort* hrow = hidS + j * 72 + sub * 16;
            uint4 ha = *(const uint4*)hrow;
            uint4 hc = *(const uint4*)(hrow + 8);
            const float* qwp = &qwS[h * 64 + sub * 16];
            float d2 = dot8(ha, qwp) + dot8(hc, qwp + 8);
            float pp = d1 + d2;
            pp += __shfl_xor(pp, 1, 64);
            pp += __shfl_xor(pp, 2, 64);
            pp *= 0.125f;
            float mx = pp;
            mx = fmaxf(mx, __shfl_xor(mx, 4, 64));
            mx = fmaxf(mx, __shfl_xor(mx, 8, 64));
            mx = fmaxf(mx, __shfl_xor(mx, 16, 64));
            mx = fmaxf(mx, __shfl_xor(mx, 32, 64));
            float e = expf(pp - mx);
            float ss = e;
            ss += __shfl_xor(ss, 4, 64);
            ss += __shfl_xor(ss, 8, 64);
            ss += __shfl_xor(ss, 16, 64);
            ss += __shfl_xor(ss, 32, 64);
            float pj = e / ss;
            if (sub == 0) psS[h * 16 + j] = pj;
        }
        __syncthreads();

        // partial + hp
        {
            float o = 0.f, hpv = 0.f;
            #pragma unroll
            for (int j = 0; j < 16; ++j) {
                float p = psS[h * 16 + j];
                int m = nbAll[pt * 16 + j];
                o   += p * b2f(vb[(base + m) * 256 + t]);
                hpv += p * b2f(hidS[j * 72 + lane]);
            }
            ab[(size_t)bn * 512 + t]       = f2b(o);
            ab[(size_t)bn * 512 + 256 + t] = f2b(hpv);
        }
        __syncthreads();
    }
}

// ---------------------------------------------------------------------------
extern "C" void kernel_launch(void* const* d_in, const int* in_sizes, int n_in,
                              void* d_out, int out_size, void* d_ws, size_t ws_size,
                              hipStream_t stream) {
    const float* xyz    = (const float*)d_in[0];
    const float* feats  = (const float*)d_in[1];
    const float* ln_q_g = (const float*)d_in[2];
    const float* ln_q_b = (const float*)d_in[3];
    const float* Wq     = (const float*)d_in[4];
    const float* bq     = (const float*)d_in[5];
    const float* Wk     = (const float*)d_in[6];
    const float* bk     = (const float*)d_in[7];
    const float* Wv     = (const float*)d_in[8];
    const float* bv     = (const float*)d_in[9];
    const float* W_rel1 = (const float*)d_in[10];
    const float* b_rel1 = (const float*)d_in[11];
    const float* W_rel2 = (const float*)d_in[12];
    const float* b_rel2 = (const float*)d_in[13];
    const float* Wo     = (const float*)d_in[14];
    const float* bo     = (const float*)d_in[15];
    const float* ln_f_g = (const float*)d_in[16];
    const float* ln_f_b = (const float*)d_in[17];
    const float* W_ff1  = (const float*)d_in[18];
    const float* b_ff1  = (const float*)d_in[19];
    const float* W_ff2  = (const float*)d_in[20];
    const float* b_ff2  = (const float*)d_in[21];
    (void)in_sizes; (void)n_in; (void)out_size; (void)ws_size;

    char* ws = (char*)d_ws;
    const size_t MB = 1u << 20;
    int*    idx    = (int*)ws;                       // 1 MB
    ushort* xb     = (ushort*)(ws + 1 * MB);         // 8 MB  (LN out)
    ushort* qb     = (ushort*)(ws + 9 * MB);         // 8 MB  (q; reused as h)
    ushort* kb     = (ushort*)(ws + 17 * MB);        // 8 MB
    ushort* vb     = (ushort*)(ws + 25 * MB);        // 8 MB
    ushort* hidg   = (ushort*)(ws + 33 * MB);        // 32 MB (hid; reused as ff1 out)
    float*  feats1 = (float*)(ws + 65 * MB);         // 16 MB
    ushort* ab     = (ushort*)(ws + 81 * MB);        // 16 MB [16384][512]; right half = qwg
    ushort* WqT    = (ushort*)(ws + 97 * MB);        // weights below
    ushort* WkT    = WqT + 65536;
    ushort* WvT    = WkT + 65536;
    ushort* WoT    = WvT + 65536;
    ushort* Wf1T   = WoT + 65536;                    // [1024][256]
    ushort* Wf2T   = Wf1T + 262144;                  // [256][1024]
    ushort* Wq_bf  = Wf2T + 262144;                  // [256][256] row-major
    ushort* w2bd   = Wq_bf + 65536;                  // [256][256]
    ushort* WqwT   = w2bd + 65536;                   // [256][256]
    ushort* BtCat  = WqwT + 65536;                   // [256][512]
    float*  bqw    = (float*)(BtCat + 131072);       // 256
    float*  boc    = bqw + 256;                      // 256
    ushort* hb   = qb;
    ushort* ff1b = hidg;

    // ---- weight preprocessing ----
    tconv<<<dim3(8, 8),  256, 0, stream>>>(Wq, WqT, 256, 256);
    tconv<<<dim3(8, 8),  256, 0, stream>>>(Wk, WkT, 256, 256);
    tconv<<<dim3(8, 8),  256, 0, stream>>>(Wv, WvT, 256, 256);
    tconv<<<dim3(8, 8),  256, 0, stream>>>(Wo, WoT, 256, 256);
    tconv<<<dim3(32, 8), 256, 0, stream>>>(W_ff1, Wf1T, 256, 1024);
    tconv<<<dim3(8, 32), 256, 0, stream>>>(W_ff2, Wf2T, 1024, 256);
    conv_k<<<256, 256, 0, stream>>>(Wq, Wq_bf);
    w2bd_kernel<<<256, 256, 0, stream>>>(W_rel2, w2bd);
    // WqwT[n][e] = sum_d w2bd[n][d] * Wq[e][d]
    gemm_bt<0, 1, 0><<<dim3(2, 2), 256, 0, stream>>>(w2bd, Wq_bf, nullptr, nullptr, WqwT, 256, 256, 256, 256);
    // BtCat right: W2Wo[col][n] = sum_d WoT[col][d] * w2bd[n][d]
    gemm_bt<0, 1, 0><<<dim3(2, 2), 256, 0, stream>>>(WoT, w2bd, nullptr, nullptr, BtCat + 256, 256, 256, 256, 512);
    catL_kernel<<<256, 256, 0, stream>>>(WoT, BtCat);
    bqw_kernel<<<1, 256, 0, stream>>>(bq, W_rel2, bqw);
    bocat_kernel<<<1, 256, 0, stream>>>(bo, b_rel2, Wo, boc);

    // ---- main pipeline ----
    knn_kernel<<<MTOT / QPB, 256, 0, stream>>>(xyz, idx);
    ln_kernel<<<MTOT, 256, 0, stream>>>(feats, ln_q_g, ln_q_b, xb);

    gemm_bt<0, 1, 0><<<dim3(2, 128), 256, 0, stream>>>(xb, WqT, bq, nullptr, qb, MTOT, 256, 256, 256);
    gemm_bt<0, 1, 0><<<dim3(2, 128), 256, 0, stream>>>(xb, WkT, bk, nullptr, kb, MTOT, 256, 256, 256);
    gemm_bt<0, 1, 0><<<dim3(2, 128), 256, 0, stream>>>(xb, WvT, bv, nullptr, vb, MTOT, 256, 256, 256);
    // qwg -> ab right half
    gemm_bt<0, 1, 0><<<dim3(2, 128), 256, 0, stream>>>(xb, WqwT, bqw, nullptr, ab + 256, MTOT, 256, 256, 512);

    hid_kernel<<<MTOT * 16 / 4, 256, 0, stream>>>(xyz, idx, W_rel1, b_rel1, hidg);
    attn_kernel<<<MTOT / PTS, 256, 0, stream>>>(idx, qb, kb, vb, hidg, ab);

    // feats1 = [partial|hp] @ BtCat^T + boc + feats
    gemm_bt<0, 0, 1><<<dim3(2, 128), 256, 0, stream>>>(ab, BtCat, boc, feats, feats1, MTOT, 256, 512, 256);
    ln_kernel<<<MTOT, 256, 0, stream>>>(feats1, ln_f_g, ln_f_b, hb);
    gemm_bt<1, 1, 0><<<dim3(8, 128), 256, 0, stream>>>(hb, Wf1T, b_ff1, nullptr, ff1b, MTOT, 1024, 256, 1024);
    gemm_bt<0, 0, 1><<<dim3(2, 128), 256, 0, stream>>>(ff1b, Wf2T, b_ff2, feats1, (float*)d_out, MTOT, 256, 1024, 256);
}

// Round 9
// 322.172 us; speedup vs baseline: 1.0940x; 1.0940x over previous
//
#include <hip/hip_runtime.h>
#include <hip/hip_bf16.h>
#include <math.h>

#define NB 4
#define NPTS 4096
#define DIM 256
#define KNN 16
#define HID 64
#define FFDIM 1024
#define LN_EPS 1e-5f
#define MTOT (NB * NPTS)
#define KINF 3e38f
#define QPB 8

typedef __attribute__((ext_vector_type(8))) short short8;
typedef __attribute__((ext_vector_type(4))) float f32x4;

__device__ __forceinline__ float gelu_f(float x) {
    return 0.5f * x * (1.0f + erff(x * 0.7071067811865476f));
}
__device__ __forceinline__ float b2f(ushort u) {
    return __uint_as_float(((unsigned)u) << 16);
}
__device__ __forceinline__ ushort f2b(float f) {
    unsigned u = __float_as_uint(f);
    return (ushort)((u + 0x7fffu + ((u >> 16) & 1u)) >> 16);
}
__device__ __forceinline__ void gload16(const void* g, void* l) {
    __builtin_amdgcn_global_load_lds((const __attribute__((address_space(1))) void*)g,
                                     (__attribute__((address_space(3))) void*)l, 16, 0, 0);
}
// dot of 8 bf16 (packed in uint4) with 8 consecutive f32
__device__ __forceinline__ float dot8(uint4 w, const float* q) {
    float s = 0.f;
    s += b2f((ushort)(w.x & 0xffff)) * q[0]; s += b2f((ushort)(w.x >> 16)) * q[1];
    s += b2f((ushort)(w.y & 0xffff)) * q[2]; s += b2f((ushort)(w.y >> 16)) * q[3];
    s += b2f((ushort)(w.z & 0xffff)) * q[4]; s += b2f((ushort)(w.z >> 16)) * q[5];
    s += b2f((ushort)(w.w & 0xffff)) * q[6]; s += b2f((ushort)(w.w >> 16)) * q[7];
    return s;
}

// ---------------------------------------------------------------------------
// KNN v5 (validated round 8; 65 us, latency-bound — left as-is this round)
// ---------------------------------------------------------------------------
__global__ __launch_bounds__(256) void knn_kernel(const float* __restrict__ xyz,
                                                  int* __restrict__ idx_out) {
    int blk = blockIdx.x;
    int bq0 = blk * QPB;
    int b = bq0 >> 12;
    const float* base = xyz + (size_t)b * NPTS * 3;
    int t = threadIdx.x;
    int lane = t & 63, wv = t >> 6;

    __shared__ float TwS[4];
    __shared__ int   cnt[QPB];
    __shared__ float cV[QPB][64];
    __shared__ int   cI[QPB][64];

    if (t < QPB) cnt[t] = 0;

    float px[16], py[16], pz[16], sq[16];
    #pragma unroll
    for (int i = 0; i < 16; ++i) {
        int m = t + 256 * i;
        px[i] = base[m * 3 + 0];
        py[i] = base[m * 3 + 1];
        pz[i] = base[m * 3 + 2];
        sq[i] = px[i] * px[i] + py[i] * py[i] + pz[i] * pz[i];
    }
    __syncthreads();

    #pragma unroll 1
    for (int qi = 0; qi < QPB; ++qi) {
        int bn = bq0 + qi;
        int n = bn & (NPTS - 1);
        float qx = base[n * 3 + 0], qy = base[n * 3 + 1], qz = base[n * 3 + 2];
        float sqn = qx * qx + qy * qy + qz * qz;

        float d[16];
        #pragma unroll
        for (int i = 0; i < 16; ++i) {
            int m = t + 256 * i;
            float dot = px[i] * qx + py[i] * qy + pz[i] * qz;
            float dd = (sqn + sq[i]) - 2.0f * dot;
            d[i] = (m == n) ? KINF : dd;
        }
        float lmin = d[0];
        #pragma unroll
        for (int i = 1; i < 16; ++i) lmin = fminf(lmin, d[i]);

        float v = lmin;
        #pragma unroll
        for (int k = 2; k <= 64; k <<= 1) {
            #pragma unroll
            for (int j = 32; j > 0; j >>= 1) {
                if (j < k) {
                    float ov = __shfl_xor(v, j, 64);
                    bool keepMin = ((lane & k) == 0) == ((lane & j) == 0);
                    if (keepMin == (ov < v)) v = ov;
                }
            }
        }
        if (lane == 15) TwS[wv] = v;
        __syncthreads();

        float T = fminf(fminf(TwS[0], TwS[1]), fminf(TwS[2], TwS[3]));
        #pragma unroll
        for (int i = 0; i < 16; ++i) {
            if (d[i] <= T) {
                int pos = atomicAdd(&cnt[qi], 1);
                if (pos < 64) { cV[qi][pos] = d[i]; cI[qi][pos] = t + 256 * i; }
            }
        }
        __syncthreads();
    }

    #pragma unroll
    for (int rep = 0; rep < 2; ++rep) {
        int qi = wv + 4 * rep;
        int nc = cnt[qi]; nc = nc > 64 ? 64 : nc;
        float v = (lane < nc) ? cV[qi][lane] : KINF;
        int   m = (lane < nc) ? cI[qi][lane] : 0x7fffffff;
        #pragma unroll
        for (int k = 2; k <= 64; k <<= 1) {
            #pragma unroll
            for (int j = 32; j > 0; j >>= 1) {
                if (j < k) {
                    float ov = __shfl_xor(v, j, 64);
                    int   om = __shfl_xor(m, j, 64);
                    bool keepMin = ((lane & k) == 0) == ((lane & j) == 0);
                    bool less = (ov < v) || (ov == v && om < m);
                    if (keepMin == less) { v = ov; m = om; }
                }
            }
        }
        if (lane < KNN) idx_out[(size_t)(bq0 + qi) * KNN + lane] = m;
    }
}

// ---------------------------------------------------------------------------
// LayerNorm f32 in -> bf16 out
// ---------------------------------------------------------------------------
__global__ __launch_bounds__(256) void ln_kernel(const float* __restrict__ in,
                                                 const float* __restrict__ g,
                                                 const float* __restrict__ bb,
                                                 ushort* __restrict__ out) {
    int r = blockIdx.x;
    int t = threadIdx.x;
    float v = in[(size_t)r * DIM + t];

    __shared__ float sw[4];
    __shared__ float sw2[4];

    float s = v;
    #pragma unroll
    for (int off = 32; off > 0; off >>= 1) s += __shfl_down(s, off);
    if ((t & 63) == 0) sw[t >> 6] = s;
    __syncthreads();
    float mean = (sw[0] + sw[1] + sw[2] + sw[3]) * (1.0f / DIM);

    float dlt = v - mean;
    float s2 = dlt * dlt;
    #pragma unroll
    for (int off = 32; off > 0; off >>= 1) s2 += __shfl_down(s2, off);
    if ((t & 63) == 0) sw2[t >> 6] = s2;
    __syncthreads();
    float var = (sw2[0] + sw2[1] + sw2[2] + sw2[3]) * (1.0f / DIM);

    out[(size_t)r * DIM + t] = f2b(dlt * rsqrtf(var + LN_EPS) * g[t] + bb[t]);
}

// ---------------------------------------------------------------------------
// Batched transpose-convert (4x 256x256): f32 in[256][256] -> bf16 out[256][256]^T
// ---------------------------------------------------------------------------
__global__ __launch_bounds__(256) void tconv4(const float* __restrict__ s0,
                                              const float* __restrict__ s1,
                                              const float* __restrict__ s2,
                                              const float* __restrict__ s3,
                                              ushort* __restrict__ d0,
                                              ushort* __restrict__ d1,
                                              ushort* __restrict__ d2,
                                              ushort* __restrict__ d3) {
    const float* in; ushort* out;
    switch (blockIdx.z) {
        case 0: in = s0; out = d0; break;
        case 1: in = s1; out = d1; break;
        case 2: in = s2; out = d2; break;
        default: in = s3; out = d3; break;
    }
    __shared__ float tile[32][33];
    int tx = threadIdx.x & 31, ty = threadIdx.x >> 5;
    int r0 = blockIdx.y * 32, c0 = blockIdx.x * 32;
    #pragma unroll
    for (int k = 0; k < 4; ++k)
        tile[ty + 8 * k][tx] = in[(size_t)(r0 + ty + 8 * k) * 256 + c0 + tx];
    __syncthreads();
    #pragma unroll
    for (int k = 0; k < 4; ++k)
        out[(size_t)(c0 + ty + 8 * k) * 256 + r0 + tx] = f2b(tile[tx][ty + 8 * k]);
}

// generic tconv for FF weights
__global__ __launch_bounds__(256) void tconv(const float* __restrict__ in,
                                             ushort* __restrict__ out, int R, int C) {
    __shared__ float tile[32][33];
    int tx = threadIdx.x & 31, ty = threadIdx.x >> 5;
    int r0 = blockIdx.y * 32, c0 = blockIdx.x * 32;
    #pragma unroll
    for (int k = 0; k < 4; ++k)
        tile[ty + 8 * k][tx] = in[(size_t)(r0 + ty + 8 * k) * C + c0 + tx];
    __syncthreads();
    #pragma unroll
    for (int k = 0; k < 4; ++k)
        out[(size_t)(c0 + ty + 8 * k) * R + r0 + tx] = f2b(tile[tx][ty + 8 * k]);
}

// merged: w2bd rows (0..255) | Wq row-major bf16 (256..511) | catL copy (512..767)
__global__ __launch_bounds__(256) void prep_mats(const float* __restrict__ W2,
                                                 const float* __restrict__ Wq,
                                                 const ushort* __restrict__ WoT,
                                                 ushort* __restrict__ w2bd,
                                                 ushort* __restrict__ Wq_bf,
                                                 ushort* __restrict__ BtCat) {
    int bb = blockIdx.x, t = threadIdx.x;
    if (bb < 256) {
        float v = ((t >> 6) == (bb >> 6)) ? W2[(bb & 63) * 256 + t] : 0.0f;
        w2bd[bb * 256 + t] = f2b(v);
    } else if (bb < 512) {
        int r = bb - 256;
        Wq_bf[r * 256 + t] = f2b(Wq[r * 256 + t]);
    } else {
        int r = bb - 512;
        BtCat[(size_t)r * 512 + t] = WoT[r * 256 + t];
    }
}

// merged biases: blocks 0..2 copy bq/bk/bv; 3 computes bqw; 4 computes boc
__global__ __launch_bounds__(256) void prep_bias(const float* __restrict__ bq,
                                                 const float* __restrict__ bk,
                                                 const float* __restrict__ bv,
                                                 const float* __restrict__ W2,
                                                 const float* __restrict__ bo,
                                                 const float* __restrict__ br2,
                                                 const float* __restrict__ Wo,
                                                 float* __restrict__ bqkvw,
                                                 float* __restrict__ boc) {
    int bb = blockIdx.x, t = threadIdx.x;
    if (bb == 0) bqkvw[t] = bq[t];
    else if (bb == 1) bqkvw[256 + t] = bk[t];
    else if (bb == 2) bqkvw[512 + t] = bv[t];
    else if (bb == 3) {
        int h = t >> 6, i = t & 63;
        float s = 0.f;
        #pragma unroll 8
        for (int dp = 0; dp < 64; ++dp) s += bq[h * 64 + dp] * W2[i * 256 + h * 64 + dp];
        bqkvw[768 + t] = s;
    } else {
        float s = bo[t];
        #pragma unroll 8
        for (int d = 0; d < 256; ++d) s += br2[d] * Wo[d * 256 + t];
        boc[t] = s;
    }
}

// ---------------------------------------------------------------------------
// MFMA bf16 GEMM: C[M][ldc] = act(A[M][K] @ Bt[N][K]^T + bias) (+res)
// ---------------------------------------------------------------------------
template <int ACT, int OUTBF, int RES>
__global__ __launch_bounds__(256) void gemm_bt(
    const ushort* __restrict__ A, const ushort* __restrict__ Bt,
    const float* __restrict__ bias, const float* __restrict__ res,
    void* __restrict__ Cv, int M, int N, int K, int ldc)
{
    __shared__ ushort As[4096];   // [128][32] bf16, swizzled
    __shared__ ushort Bs[4096];
    const int t = threadIdx.x;
    const int wave = t >> 6, lane = t & 63;
    const int m0 = blockIdx.y * 128, n0 = blockIdx.x * 128;
    const int wr = (wave >> 1) * 64, wc = (wave & 1) * 64;

    f32x4 acc[4][4];
    #pragma unroll
    for (int i = 0; i < 4; ++i)
        #pragma unroll
        for (int j = 0; j < 4; ++j) acc[i][j] = {0.f, 0.f, 0.f, 0.f};

    const int rA0 = (wave * 2 + 0) * 16 + (lane >> 2);
    const int rA1 = (wave * 2 + 1) * 16 + (lane >> 2);
    const int u4 = lane & 3;
    const int sw0 = (rA0 + (rA0 >> 2)) & 3;
    const int sw1 = (rA1 + (rA1 >> 2)) & 3;
    char* ldsA0 = (char*)As + (wave * 2 + 0) * 1024 + lane * 16;
    char* ldsA1 = (char*)As + (wave * 2 + 1) * 1024 + lane * 16;
    char* ldsB0 = (char*)Bs + (wave * 2 + 0) * 1024 + lane * 16;
    char* ldsB1 = (char*)Bs + (wave * 2 + 1) * 1024 + lane * 16;
    const size_t aOff0 = (size_t)(m0 + rA0) * K + (size_t)((u4 ^ sw0) * 8);
    const size_t aOff1 = (size_t)(m0 + rA1) * K + (size_t)((u4 ^ sw1) * 8);
    const size_t bOff0 = (size_t)(n0 + rA0) * K + (size_t)((u4 ^ sw0) * 8);
    const size_t bOff1 = (size_t)(n0 + rA1) * K + (size_t)((u4 ^ sw1) * 8);

    const int cl = lane & 15, gq = lane >> 4;

    for (int k0 = 0; k0 < K; k0 += 32) {
        gload16(A + aOff0 + k0, ldsA0);
        gload16(A + aOff1 + k0, ldsA1);
        gload16(Bt + bOff0 + k0, ldsB0);
        gload16(Bt + bOff1 + k0, ldsB1);
        __syncthreads();

        short8 av[4], bv[4];
        #pragma unroll
        for (int mi = 0; mi < 4; ++mi) {
            int row = wr + mi * 16 + cl;
            int s = (row + (row >> 2)) & 3;
            av[mi] = *(const short8*)((const char*)As + row * 64 + ((gq ^ s) << 4));
            int rowb = wc + mi * 16 + cl;
            int sb = (rowb + (rowb >> 2)) & 3;
            bv[mi] = *(const short8*)((const char*)Bs + rowb * 64 + ((gq ^ sb) << 4));
        }
        #pragma unroll
        for (int mi = 0; mi < 4; ++mi)
            #pragma unroll
            for (int ni = 0; ni < 4; ++ni)
                acc[mi][ni] = __builtin_amdgcn_mfma_f32_16x16x32_bf16(av[mi], bv[ni], acc[mi][ni], 0, 0, 0);
        __syncthreads();
    }

    float* Cf = (float*)Cv;
    ushort* Cb = (ushort*)Cv;
    #pragma unroll
    for (int ni = 0; ni < 4; ++ni) {
        int col = n0 + wc + ni * 16 + cl;
        float bvv = bias ? bias[col] : 0.0f;
        #pragma unroll
        for (int mi = 0; mi < 4; ++mi) {
            #pragma unroll
            for (int r = 0; r < 4; ++r) {
                int row = m0 + wr + mi * 16 + gq * 4 + r;
                float v = acc[mi][ni][r] + bvv;
                if (ACT == 1) v = gelu_f(v);
                if (RES) v += res[(size_t)row * N + col];
                if (OUTBF) Cb[(size_t)row * ldc + col] = f2b(v);
                else       Cf[(size_t)row * ldc + col] = v;
            }
        }
    }
}

// ---------------------------------------------------------------------------
// hid = gelu(rel @ W_rel1 + b_rel1) -> bf16
// ---------------------------------------------------------------------------
__global__ __launch_bounds__(256) void hid_kernel(const float* __restrict__ xyz,
                                                  const int* __restrict__ idx,
                                                  const float* __restrict__ W1,
                                                  const float* __restrict__ b1,
                                                  ushort* __restrict__ hid) {
    int t = threadIdx.x;
    int rl = t >> 6, i = t & 63;
    int row = blockIdx.x * 4 + rl;
    int bn = row >> 4;
    int b = bn >> 12;
    int n = bn & (NPTS - 1);
    int m = idx[row];
    const float* xb = xyz + (size_t)b * NPTS * 3;
    float dx = xb[m * 3 + 0] - xb[n * 3 + 0];
    float dy = xb[m * 3 + 1] - xb[n * 3 + 1];
    float dz = xb[m * 3 + 2] - xb[n * 3 + 2];
    float nr = sqrtf(dx * dx + dy * dy + dz * dz);
    float a = b1[i] + dx * W1[i] + dy * W1[64 + i] + dz * W1[128 + i] + nr * W1[192 + i];
    hid[(size_t)row * 64 + i] = f2b(gelu_f(a));
}

// ---------------------------------------------------------------------------
// Attention v3: q/k/v/qw all from fused qkvw[16384][1024] (offsets 0/256/512/768).
// outputs: ab[bn][0:256] = partial, ab[bn][256:512] = hp.
// ---------------------------------------------------------------------------
#define PTS 8
__global__ __launch_bounds__(256) void attn_kernel(
    const int* __restrict__ idx,
    const ushort* __restrict__ qkvw, const ushort* __restrict__ hidg,
    ushort* __restrict__ ab)
{
    __shared__ float qS[256];
    __shared__ float qwS[256];
    __shared__ float psS[64];
    __shared__ uint4 hidS4[16 * 9];
    __shared__ int   nbAll[128];
    ushort* hidS = (ushort*)hidS4;

    const int t = threadIdx.x;
    const int h = t >> 6, lane = t & 63;
    const int bid = blockIdx.x;
    const int blk = ((bid & 7) << 8) | (bid >> 3);   // XCD-contiguous, bijective
    const int bn0 = blk * PTS;
    const int R0 = blk * (PTS * 16);

    if (t < 128) nbAll[t] = idx[R0 + t];

    for (int pt = 0; pt < PTS; ++pt) {
        const int bn = bn0 + pt;
        const size_t base = (size_t)(bn >> 12) * NPTS;

        qS[t]  = b2f(qkvw[(size_t)bn * 1024 + t]);
        qwS[t] = b2f(qkvw[(size_t)bn * 1024 + 768 + t]);
        if (t < 128) {
            int j = t >> 3, c = t & 7;
            hidS4[j * 9 + c] = *(const uint4*)(hidg + (size_t)(R0 + pt * 16 + j) * 64 + c * 8);
        }
        __syncthreads();

        // logits + softmax (wave h = head h; lane = j*4+sub)
        {
            int j = lane >> 2, sub = lane & 3;
            int m = nbAll[pt * 16 + j];
            const ushort* krow = qkvw + (base + m) * 1024 + 256 + h * 64 + sub * 16;
            uint4 ka = *(const uint4*)krow;
            uint4 kc = *(const uint4*)(krow + 8);
            const float* qp = &qS[h * 64 + sub * 16];
            float d1 = dot8(ka, qp) + dot8(kc, qp + 8);
            const ushort* hrow = hidS + j * 72 + sub * 16;
            uint4 ha = *(const uint4*)hrow;
            uint4 hc = *(const uint4*)(hrow + 8);
            const float* qwp = &qwS[h * 64 + sub * 16];
            float d2 = dot8(ha, qwp) + dot8(hc, qwp + 8);
            float pp = d1 + d2;
            pp += __shfl_xor(pp, 1, 64);
            pp += __shfl_xor(pp, 2, 64);
            pp *= 0.125f;
            float mx = pp;
            mx = fmaxf(mx, __shfl_xor(mx, 4, 64));
            mx = fmaxf(mx, __shfl_xor(mx, 8, 64));
            mx = fmaxf(mx, __shfl_xor(mx, 16, 64));
            mx = fmaxf(mx, __shfl_xor(mx, 32, 64));
            float e = expf(pp - mx);
            float ss = e;
            ss += __shfl_xor(ss, 4, 64);
            ss += __shfl_xor(ss, 8, 64);
            ss += __shfl_xor(ss, 16, 64);
            ss += __shfl_xor(ss, 32, 64);
            float pj = e / ss;
            if (sub == 0) psS[h * 16 + j] = pj;
        }
        __syncthreads();

        // partial + hp
        {
            float o = 0.f, hpv = 0.f;
            #pragma unroll
            for (int j = 0; j < 16; ++j) {
                float p = psS[h * 16 + j];
                int m = nbAll[pt * 16 + j];
                o   += p * b2f(qkvw[(base + m) * 1024 + 512 + t]);
                hpv += p * b2f(hidS[j * 72 + lane]);
            }
            ab[(size_t)bn * 512 + t]       = f2b(o);
            ab[(size_t)bn * 512 + 256 + t] = f2b(hpv);
        }
        __syncthreads();
    }
}

// ---------------------------------------------------------------------------
extern "C" void kernel_launch(void* const* d_in, const int* in_sizes, int n_in,
                              void* d_out, int out_size, void* d_ws, size_t ws_size,
                              hipStream_t stream) {
    const float* xyz    = (const float*)d_in[0];
    const float* feats  = (const float*)d_in[1];
    const float* ln_q_g = (const float*)d_in[2];
    const float* ln_q_b = (const float*)d_in[3];
    const float* Wq     = (const float*)d_in[4];
    const float* bq     = (const float*)d_in[5];
    const float* Wk     = (const float*)d_in[6];
    const float* bk     = (const float*)d_in[7];
    const float* Wv     = (const float*)d_in[8];
    const float* bv     = (const float*)d_in[9];
    const float* W_rel1 = (const float*)d_in[10];
    const float* b_rel1 = (const float*)d_in[11];
    const float* W_rel2 = (const float*)d_in[12];
    const float* b_rel2 = (const float*)d_in[13];
    const float* Wo     = (const float*)d_in[14];
    const float* bo     = (const float*)d_in[15];
    const float* ln_f_g = (const float*)d_in[16];
    const float* ln_f_b = (const float*)d_in[17];
    const float* W_ff1  = (const float*)d_in[18];
    const float* b_ff1  = (const float*)d_in[19];
    const float* W_ff2  = (const float*)d_in[20];
    const float* b_ff2  = (const float*)d_in[21];
    (void)in_sizes; (void)n_in; (void)out_size; (void)ws_size;

    char* ws = (char*)d_ws;
    const size_t MB = 1u << 20;
    int*    idx    = (int*)ws;                        // 1 MB
    ushort* xb     = (ushort*)(ws + 1 * MB);          // 8 MB  (LN out; reused as h)
    ushort* qkvw   = (ushort*)(ws + 9 * MB);          // 32 MB [16384][1024]; feats1 overlays
    ushort* hidg   = (ushort*)(ws + 41 * MB);         // 32 MB (hid; reused as ff1 out)
    ushort* ab     = (ushort*)(ws + 73 * MB);         // 16 MB [16384][512]
    ushort* BtQKVW = (ushort*)(ws + 89 * MB);         // [1024][256] = 512 KB
    ushort* WoT    = BtQKVW + 262144;                 // 128 KB
    ushort* Wf1T   = WoT + 65536;                     // [1024][256] 512 KB
    ushort* Wf2T   = Wf1T + 262144;                   // [256][1024] 512 KB
    ushort* Wq_bf  = Wf2T + 262144;                   // 128 KB
    ushort* w2bd   = Wq_bf + 65536;                   // 128 KB
    ushort* BtCat  = w2bd + 65536;                    // [256][512] 256 KB
    float*  bqkvw  = (float*)(BtCat + 131072);        // 1024 f32
    float*  boc    = bqkvw + 1024;                    // 256 f32
    float*  feats1 = (float*)(ws + 9 * MB);           // overlays qkvw (dead by then)
    ushort* hb     = xb;                              // overlays xb (dead by then)
    ushort* ff1b   = hidg;                            // overlays hidg (dead by then)

    // ---- weight preprocessing ----
    tconv4<<<dim3(8, 8, 4), 256, 0, stream>>>(Wq, Wk, Wv, Wo,
                                              BtQKVW, BtQKVW + 65536, BtQKVW + 131072, WoT);
    tconv<<<dim3(32, 8), 256, 0, stream>>>(W_ff1, Wf1T, 256, 1024);
    tconv<<<dim3(8, 32), 256, 0, stream>>>(W_ff2, Wf2T, 1024, 256);
    prep_mats<<<768, 256, 0, stream>>>(W_rel2, Wq, WoT, w2bd, Wq_bf, BtCat);
    // WqwT -> BtQKVW rows 768..1023
    gemm_bt<0, 1, 0><<<dim3(2, 2), 256, 0, stream>>>(w2bd, Wq_bf, nullptr, nullptr,
                                                     BtQKVW + 768 * 256, 256, 256, 256, 256);
    // W2Wo -> BtCat right half
    gemm_bt<0, 1, 0><<<dim3(2, 2), 256, 0, stream>>>(WoT, w2bd, nullptr, nullptr,
                                                     BtCat + 256, 256, 256, 256, 512);
    prep_bias<<<5, 256, 0, stream>>>(bq, bk, bv, W_rel2, bo, b_rel2, Wo, bqkvw, boc);

    // ---- main pipeline ----
    knn_kernel<<<MTOT / QPB, 256, 0, stream>>>(xyz, idx);
    ln_kernel<<<MTOT, 256, 0, stream>>>(feats, ln_q_g, ln_q_b, xb);

    // fused q|k|v|qw GEMM: [16384][1024]
    gemm_bt<0, 1, 0><<<dim3(8, 128), 256, 0, stream>>>(xb, BtQKVW, bqkvw, nullptr,
                                                       qkvw, MTOT, 1024, 256, 1024);

    hid_kernel<<<MTOT * 16 / 4, 256, 0, stream>>>(xyz, idx, W_rel1, b_rel1, hidg);
    attn_kernel<<<MTOT / PTS, 256, 0, stream>>>(idx, qkvw, hidg, ab);

    // feats1 = [partial|hp] @ BtCat^T + boc + feats   (overlays qkvw)
    gemm_bt<0, 0, 1><<<dim3(2, 128), 256, 0, stream>>>(ab, BtCat, boc, feats, feats1, MTOT, 256, 512, 256);
    ln_kernel<<<MTOT, 256, 0, stream>>>(feats1, ln_f_g, ln_f_b, hb);
    gemm_bt<1, 1, 0><<<dim3(8, 128), 256, 0, stream>>>(hb, Wf1T, b_ff1, nullptr, ff1b, MTOT, 1024, 256, 1024);
    gemm_bt<0, 0, 1><<<dim3(2, 128), 256, 0, stream>>>(ff1b, Wf2T, b_ff2, feats1, (float*)d_out, MTOT, 256, 1024, 256);
}

// Round 12
// 288.446 us; speedup vs baseline: 1.2219x; 1.1169x over previous
//
#include <hip/hip_runtime.h>
#include <hip/hip_bf16.h>
#include <math.h>

#define NB 4
#define NPTS 4096
#define DIM 256
#define KNN 16
#define HID 64
#define FFDIM 1024
#define LN_EPS 1e-5f
#define MTOT (NB * NPTS)
#define KINF 3e38f
#define QPB 8

typedef __attribute__((ext_vector_type(8))) short short8;
typedef __attribute__((ext_vector_type(4))) float f32x4;

__device__ __forceinline__ float gelu_f(float x) {
    return 0.5f * x * (1.0f + erff(x * 0.7071067811865476f));
}
__device__ __forceinline__ float b2f(ushort u) {
    return __uint_as_float(((unsigned)u) << 16);
}
__device__ __forceinline__ ushort f2b(float f) {
    unsigned u = __float_as_uint(f);
    return (ushort)((u + 0x7fffu + ((u >> 16) & 1u)) >> 16);
}
__device__ __forceinline__ void gload16(const void* g, void* l) {
    __builtin_amdgcn_global_load_lds((const __attribute__((address_space(1))) void*)g,
                                     (__attribute__((address_space(3))) void*)l, 16, 0, 0);
}
// dot of 8 bf16 (packed in uint4) with 8 consecutive f32
__device__ __forceinline__ float dot8(uint4 w, const float* q) {
    float s = 0.f;
    s += b2f((ushort)(w.x & 0xffff)) * q[0]; s += b2f((ushort)(w.x >> 16)) * q[1];
    s += b2f((ushort)(w.y & 0xffff)) * q[2]; s += b2f((ushort)(w.y >> 16)) * q[3];
    s += b2f((ushort)(w.z & 0xffff)) * q[4]; s += b2f((ushort)(w.z >> 16)) * q[5];
    s += b2f((ushort)(w.w & 0xffff)) * q[6]; s += b2f((ushort)(w.w >> 16)) * q[7];
    return s;
}

// ---------------------------------------------------------------------------
// KNN v7 (validated threshold rule): 8 queries/block, ILP-2 interleaved chains.
// T = block-wide 16th-smallest thread-min (exactly 16 thread-mins <= T,
// cnt ~16-20, cap 64 never hit => deterministic).
// ---------------------------------------------------------------------------
__global__ __launch_bounds__(256) void knn_kernel(const float* __restrict__ xyz,
                                                  int* __restrict__ idx_out) {
    int blk = blockIdx.x;
    int bq0 = blk * QPB;
    int b = bq0 >> 12;
    const float* base = xyz + (size_t)b * NPTS * 3;
    int t = threadIdx.x;
    int lane = t & 63, wv = t >> 6;

    __shared__ float wq0S[64];
    __shared__ float wq1S[64];
    __shared__ int   cnt[QPB];
    __shared__ float cV[QPB][64];
    __shared__ int   cI[QPB][64];

    if (t < QPB) cnt[t] = 0;

    float px[16], py[16], pz[16], sq[16];
    #pragma unroll
    for (int i = 0; i < 16; ++i) {
        int m = t + 256 * i;
        px[i] = base[m * 3 + 0];
        py[i] = base[m * 3 + 1];
        pz[i] = base[m * 3 + 2];
        sq[i] = px[i] * px[i] + py[i] * py[i] + pz[i] * pz[i];
    }
    __syncthreads();

    #pragma unroll 1
    for (int qp = 0; qp < QPB; qp += 2) {
        int n0 = (bq0 + qp)     & (NPTS - 1);
        int n1 = (bq0 + qp + 1) & (NPTS - 1);
        float q0x = base[n0 * 3 + 0], q0y = base[n0 * 3 + 1], q0z = base[n0 * 3 + 2];
        float q1x = base[n1 * 3 + 0], q1y = base[n1 * 3 + 1], q1z = base[n1 * 3 + 2];
        float sq0 = q0x * q0x + q0y * q0y + q0z * q0z;
        float sq1 = q1x * q1x + q1y * q1y + q1z * q1z;

        float d0[16], d1[16];
        #pragma unroll
        for (int i = 0; i < 16; ++i) {
            int m = t + 256 * i;
            float dot0 = px[i] * q0x + py[i] * q0y + pz[i] * q0z;
            float dot1 = px[i] * q1x + py[i] * q1y + pz[i] * q1z;
            float dd0 = (sq0 + sq[i]) - 2.0f * dot0;
            float dd1 = (sq1 + sq[i]) - 2.0f * dot1;
            d0[i] = (m == n0) ? KINF : dd0;
            d1[i] = (m == n1) ? KINF : dd1;
        }
        float lm0 = d0[0], lm1 = d1[0];
        #pragma unroll
        for (int i = 1; i < 16; ++i) { lm0 = fminf(lm0, d0[i]); lm1 = fminf(lm1, d1[i]); }

        // interleaved per-wave ascending bitonic sorts of the thread-mins
        float v0 = lm0, v1 = lm1;
        #pragma unroll
        for (int k = 2; k <= 64; k <<= 1) {
            #pragma unroll
            for (int j = 32; j > 0; j >>= 1) {
                if (j < k) {
                    float ov0 = __shfl_xor(v0, j, 64);
                    float ov1 = __shfl_xor(v1, j, 64);
                    bool keepMin = ((lane & k) == 0) == ((lane & j) == 0);
                    if (keepMin == (ov0 < v0)) v0 = ov0;
                    if (keepMin == (ov1 < v1)) v1 = ov1;
                }
            }
        }
        // wave top-16s (global top-16 thread-mins are each within their wave's top-16)
        if (lane < 16) { wq0S[wv * 16 + lane] = v0; wq1S[wv * 16 + lane] = v1; }
        __syncthreads();

        // ALL waves redundantly sort the same 64 collected values (parallel, identical)
        float s0 = wq0S[lane], s1 = wq1S[lane];
        #pragma unroll
        for (int k = 2; k <= 64; k <<= 1) {
            #pragma unroll
            for (int j = 32; j > 0; j >>= 1) {
                if (j < k) {
                    float os0 = __shfl_xor(s0, j, 64);
                    float os1 = __shfl_xor(s1, j, 64);
                    bool keepMin = ((lane & k) == 0) == ((lane & j) == 0);
                    if (keepMin == (os0 < s0)) s0 = os0;
                    if (keepMin == (os1 < s1)) s1 = os1;
                }
            }
        }
        float T0 = __shfl(s0, 15, 64);   // block 16th-smallest thread-min
        float T1 = __shfl(s1, 15, 64);

        #pragma unroll
        for (int i = 0; i < 16; ++i) {
            if (d0[i] <= T0) {
                int pos = atomicAdd(&cnt[qp], 1);
                if (pos < 64) { cV[qp][pos] = d0[i]; cI[qp][pos] = t + 256 * i; }
            }
        }
        #pragma unroll
        for (int i = 0; i < 16; ++i) {
            if (d1[i] <= T1) {
                int pos = atomicAdd(&cnt[qp + 1], 1);
                if (pos < 64) { cV[qp + 1][pos] = d1[i]; cI[qp + 1][pos] = t + 256 * i; }
            }
        }
        __syncthreads();
    }

    // final: wave w sorts queries w and w+4 (lexicographic (d, idx), 64-wide)
    #pragma unroll
    for (int rep = 0; rep < 2; ++rep) {
        int qi = wv + 4 * rep;
        int nc = cnt[qi]; nc = nc > 64 ? 64 : nc;
        float v = (lane < nc) ? cV[qi][lane] : KINF;
        int   m = (lane < nc) ? cI[qi][lane] : 0x7fffffff;
        #pragma unroll
        for (int k = 2; k <= 64; k <<= 1) {
            #pragma unroll
            for (int j = 32; j > 0; j >>= 1) {
                if (j < k) {
                    float ov = __shfl_xor(v, j, 64);
                    int   om = __shfl_xor(m, j, 64);
                    bool keepMin = ((lane & k) == 0) == ((lane & j) == 0);
                    bool less = (ov < v) || (ov == v && om < m);
                    if (keepMin == less) { v = ov; m = om; }
                }
            }
        }
        if (lane < KNN) idx_out[(size_t)(bq0 + qi) * KNN + lane] = m;
    }
}

// ---------------------------------------------------------------------------
// LayerNorm f32 in -> bf16 out
// ---------------------------------------------------------------------------
__global__ __launch_bounds__(256) void ln_kernel(const float* __restrict__ in,
                                                 const float* __restrict__ g,
                                                 const float* __restrict__ bb,
                                                 ushort* __restrict__ out) {
    int r = blockIdx.x;
    int t = threadIdx.x;
    float v = in[(size_t)r * DIM + t];

    __shared__ float sw[4];
    __shared__ float sw2[4];

    float s = v;
    #pragma unroll
    for (int off = 32; off > 0; off >>= 1) s += __shfl_down(s, off);
    if ((t & 63) == 0) sw[t >> 6] = s;
    __syncthreads();
    float mean = (sw[0] + sw[1] + sw[2] + sw[3]) * (1.0f / DIM);

    float dlt = v - mean;
    float s2 = dlt * dlt;
    #pragma unroll
    for (int off = 32; off > 0; off >>= 1) s2 += __shfl_down(s2, off);
    if ((t & 63) == 0) sw2[t >> 6] = s2;
    __syncthreads();
    float var = (sw2[0] + sw2[1] + sw2[2] + sw2[3]) * (1.0f / DIM);

    out[(size_t)r * DIM + t] = f2b(dlt * rsqrtf(var + LN_EPS) * g[t] + bb[t]);
}

// ---------------------------------------------------------------------------
// Batched transpose-convert (4x 256x256)
// ---------------------------------------------------------------------------
__global__ __launch_bounds__(256) void tconv4(const float* __restrict__ s0,
                                              const float* __restrict__ s1,
                                              const float* __restrict__ s2,
                                              const float* __restrict__ s3,
                                              ushort* __restrict__ d0,
                                              ushort* __restrict__ d1,
                                              ushort* __restrict__ d2,
                                              ushort* __restrict__ d3) {
    const float* in; ushort* out;
    switch (blockIdx.z) {
        case 0: in = s0; out = d0; break;
        case 1: in = s1; out = d1; break;
        case 2: in = s2; out = d2; break;
        default: in = s3; out = d3; break;
    }
    __shared__ float tile[32][33];
    int tx = threadIdx.x & 31, ty = threadIdx.x >> 5;
    int r0 = blockIdx.y * 32, c0 = blockIdx.x * 32;
    #pragma unroll
    for (int k = 0; k < 4; ++k)
        tile[ty + 8 * k][tx] = in[(size_t)(r0 + ty + 8 * k) * 256 + c0 + tx];
    __syncthreads();
    #pragma unroll
    for (int k = 0; k < 4; ++k)
        out[(size_t)(c0 + ty + 8 * k) * 256 + r0 + tx] = f2b(tile[tx][ty + 8 * k]);
}

// generic tconv for FF weights
__global__ __launch_bounds__(256) void tconv(const float* __restrict__ in,
                                             ushort* __restrict__ out, int R, int C) {
    __shared__ float tile[32][33];
    int tx = threadIdx.x & 31, ty = threadIdx.x >> 5;
    int r0 = blockIdx.y * 32, c0 = blockIdx.x * 32;
    #pragma unroll
    for (int k = 0; k < 4; ++k)
        tile[ty + 8 * k][tx] = in[(size_t)(r0 + ty + 8 * k) * C + c0 + tx];
    __syncthreads();
    #pragma unroll
    for (int k = 0; k < 4; ++k)
        out[(size_t)(c0 + ty + 8 * k) * R + r0 + tx] = f2b(tile[tx][ty + 8 * k]);
}

// merged: w2bd rows (0..255) | Wq row-major bf16 (256..511) | catL copy (512..767)
__global__ __launch_bounds__(256) void prep_mats(const float* __restrict__ W2,
                                                 const float* __restrict__ Wq,
                                                 const ushort* __restrict__ WoT,
                                                 ushort* __restrict__ w2bd,
                                                 ushort* __restrict__ Wq_bf,
                                                 ushort* __restrict__ BtCat) {
    int bb = blockIdx.x, t = threadIdx.x;
    if (bb < 256) {
        float v = ((t >> 6) == (bb >> 6)) ? W2[(bb & 63) * 256 + t] : 0.0f;
        w2bd[bb * 256 + t] = f2b(v);
    } else if (bb < 512) {
        int r = bb - 256;
        Wq_bf[r * 256 + t] = f2b(Wq[r * 256 + t]);
    } else {
        int r = bb - 512;
        BtCat[(size_t)r * 512 + t] = WoT[r * 256 + t];
    }
}

// merged biases
__global__ __launch_bounds__(256) void prep_bias(const float* __restrict__ bq,
                                                 const float* __restrict__ bk,
                                                 const float* __restrict__ bv,
                                                 const float* __restrict__ W2,
                                                 const float* __restrict__ bo,
                                                 const float* __restrict__ br2,
                                                 const float* __restrict__ Wo,
                                                 float* __restrict__ bqkvw,
                                                 float* __restrict__ boc) {
    int bb = blockIdx.x, t = threadIdx.x;
    if (bb == 0) bqkvw[t] = bq[t];
    else if (bb == 1) bqkvw[256 + t] = bk[t];
    else if (bb == 2) bqkvw[512 + t] = bv[t];
    else if (bb == 3) {
        int h = t >> 6, i = t & 63;
        float s = 0.f;
        #pragma unroll 8
        for (int dp = 0; dp < 64; ++dp) s += bq[h * 64 + dp] * W2[i * 256 + h * 64 + dp];
        bqkvw[768 + t] = s;
    } else {
        float s = bo[t];
        #pragma unroll 8
        for (int d = 0; d < 256; ++d) s += br2[d] * Wo[d * 256 + t];
        boc[t] = s;
    }
}

// ---------------------------------------------------------------------------
// MFMA bf16 GEMM: C[M][ldc] = act(A[M][K] @ Bt[N][K]^T + bias) (+res)
// ---------------------------------------------------------------------------
template <int ACT, int OUTBF, int RES>
__global__ __launch_bounds__(256) void gemm_bt(
    const ushort* __restrict__ A, const ushort* __restrict__ Bt,
    const float* __restrict__ bias, const float* __restrict__ res,
    void* __restrict__ Cv, int M, int N, int K, int ldc)
{
    __shared__ ushort As[4096];
    __shared__ ushort Bs[4096];
    const int t = threadIdx.x;
    const int wave = t >> 6, lane = t & 63;
    const int m0 = blockIdx.y * 128, n0 = blockIdx.x * 128;
    const int wr = (wave >> 1) * 64, wc = (wave & 1) * 64;

    f32x4 acc[4][4];
    #pragma unroll
    for (int i = 0; i < 4; ++i)
        #pragma unroll
        for (int j = 0; j < 4; ++j) acc[i][j] = {0.f, 0.f, 0.f, 0.f};

    const int rA0 = (wave * 2 + 0) * 16 + (lane >> 2);
    const int rA1 = (wave * 2 + 1) * 16 + (lane >> 2);
    const int u4 = lane & 3;
    const int sw0 = (rA0 + (rA0 >> 2)) & 3;
    const int sw1 = (rA1 + (rA1 >> 2)) & 3;
    char* ldsA0 = (char*)As + (wave * 2 + 0) * 1024 + lane * 16;
    char* ldsA1 = (char*)As + (wave * 2 + 1) * 1024 + lane * 16;
    char* ldsB0 = (char*)Bs + (wave * 2 + 0) * 1024 + lane * 16;
    char* ldsB1 = (char*)Bs + (wave * 2 + 1) * 1024 + lane * 16;
    const size_t aOff0 = (size_t)(m0 + rA0) * K + (size_t)((u4 ^ sw0) * 8);
    const size_t aOff1 = (size_t)(m0 + rA1) * K + (size_t)((u4 ^ sw1) * 8);
    const size_t bOff0 = (size_t)(n0 + rA0) * K + (size_t)((u4 ^ sw0) * 8);
    const size_t bOff1 = (size_t)(n0 + rA1) * K + (size_t)((u4 ^ sw1) * 8);

    const int cl = lane & 15, gq = lane >> 4;

    for (int k0 = 0; k0 < K; k0 += 32) {
        gload16(A + aOff0 + k0, ldsA0);
        gload16(A + aOff1 + k0, ldsA1);
        gload16(Bt + bOff0 + k0, ldsB0);
        gload16(Bt + bOff1 + k0, ldsB1);
        __syncthreads();

        short8 av[4], bv[4];
        #pragma unroll
        for (int mi = 0; mi < 4; ++mi) {
            int row = wr + mi * 16 + cl;
            int s = (row + (row >> 2)) & 3;
            av[mi] = *(const short8*)((const char*)As + row * 64 + ((gq ^ s) << 4));
            int rowb = wc + mi * 16 + cl;
            int sb = (rowb + (rowb >> 2)) & 3;
            bv[mi] = *(const short8*)((const char*)Bs + rowb * 64 + ((gq ^ sb) << 4));
        }
        #pragma unroll
        for (int mi = 0; mi < 4; ++mi)
            #pragma unroll
            for (int ni = 0; ni < 4; ++ni)
                acc[mi][ni] = __builtin_amdgcn_mfma_f32_16x16x32_bf16(av[mi], bv[ni], acc[mi][ni], 0, 0, 0);
        __syncthreads();
    }

    float* Cf = (float*)Cv;
    ushort* Cb = (ushort*)Cv;
    #pragma unroll
    for (int ni = 0; ni < 4; ++ni) {
        int col = n0 + wc + ni * 16 + cl;
        float bvv = bias ? bias[col] : 0.0f;
        #pragma unroll
        for (int mi = 0; mi < 4; ++mi) {
            #pragma unroll
            for (int r = 0; r < 4; ++r) {
                int row = m0 + wr + mi * 16 + gq * 4 + r;
                float v = acc[mi][ni][r] + bvv;
                if (ACT == 1) v = gelu_f(v);
                if (RES) v += res[(size_t)row * N + col];
                if (OUTBF) Cb[(size_t)row * ldc + col] = f2b(v);
                else       Cf[(size_t)row * ldc + col] = v;
            }
        }
    }
}

// ---------------------------------------------------------------------------
// Attention v5: hid computed in-kernel; prologue barrier added (round-11 race
// fix: hid section reads nbAll/w1S/b1S written by OTHER waves — must sync
// before first use). q/k/v/qw from fused qkvw[16384][1024].
// ---------------------------------------------------------------------------
#define PTS 8
__global__ __launch_bounds__(256) void attn_kernel(
    const int* __restrict__ idx,
    const ushort* __restrict__ qkvw,
    const float* __restrict__ xyz,
    const float* __restrict__ W1,
    const float* __restrict__ b1,
    ushort* __restrict__ ab)
{
    __shared__ float qS[256];
    __shared__ float qwS[256];
    __shared__ float psS[64];
    __shared__ uint4 hidS4[16 * 9];   // [16 rows][stride 144B]
    __shared__ int   nbAll[128];
    __shared__ float w1S[256];
    __shared__ float b1S[64];
    ushort* hidS = (ushort*)hidS4;

    const int t = threadIdx.x;
    const int h = t >> 6, lane = t & 63;
    const int bid = blockIdx.x;
    const int blk = ((bid & 7) << 8) | (bid >> 3);   // XCD-contiguous, bijective
    const int bn0 = blk * PTS;
    const int R0 = blk * (PTS * 16);

    if (t < 128) nbAll[t] = idx[R0 + t];
    w1S[t] = W1[t];
    if (t < 64) b1S[t] = b1[t];
    const float* xb3 = xyz + (size_t)(bn0 >> 12) * NPTS * 3;
    __syncthreads();   // RACE FIX: nbAll/w1S/b1S are read cross-wave below

    for (int pt = 0; pt < PTS; ++pt) {
        const int bn = bn0 + pt;
        const size_t base = (size_t)(bn >> 12) * NPTS;

        qS[t]  = b2f(qkvw[(size_t)bn * 1024 + t]);
        qwS[t] = b2f(qkvw[(size_t)bn * 1024 + 768 + t]);
        // compute hid rows for this point: j = t>>4 (16 rows), 4 dims/thread
        {
            int n = bn & (NPTS - 1);
            float nx = xb3[n * 3 + 0], ny = xb3[n * 3 + 1], nz = xb3[n * 3 + 2];
            int j = t >> 4;
            int i0 = (t & 15) * 4;
            int m = nbAll[pt * 16 + j];
            float dx = xb3[m * 3 + 0] - nx;
            float dy = xb3[m * 3 + 1] - ny;
            float dz = xb3[m * 3 + 2] - nz;
            float nr = sqrtf(dx * dx + dy * dy + dz * dz);
            uint2 hw;
            float a0 = b1S[i0 + 0] + dx * w1S[i0 + 0] + dy * w1S[64 + i0 + 0] + dz * w1S[128 + i0 + 0] + nr * w1S[192 + i0 + 0];
            float a1 = b1S[i0 + 1] + dx * w1S[i0 + 1] + dy * w1S[64 + i0 + 1] + dz * w1S[128 + i0 + 1] + nr * w1S[192 + i0 + 1];
            float a2 = b1S[i0 + 2] + dx * w1S[i0 + 2] + dy * w1S[64 + i0 + 2] + dz * w1S[128 + i0 + 2] + nr * w1S[192 + i0 + 2];
            float a3 = b1S[i0 + 3] + dx * w1S[i0 + 3] + dy * w1S[64 + i0 + 3] + dz * w1S[128 + i0 + 3] + nr * w1S[192 + i0 + 3];
            hw.x = (uint)f2b(gelu_f(a0)) | ((uint)f2b(gelu_f(a1)) << 16);
            hw.y = (uint)f2b(gelu_f(a2)) | ((uint)f2b(gelu_f(a3)) << 16);
            *(uint2*)(hidS + j * 72 + i0) = hw;
        }
        __syncthreads();

        // logits + softmax (wave h = head h; lane = j*4+sub)
        {
            int j = lane >> 2, sub = lane & 3;
            int m = nbAll[pt * 16 + j];
            const ushort* krow = qkvw + (base + m) * 1024 + 256 + h * 64 + sub * 16;
            uint4 ka = *(const uint4*)krow;
            uint4 kc = *(const uint4*)(krow + 8);
            const float* qp = &qS[h * 64 + sub * 16];
            float d1 = dot8(ka, qp) + dot8(kc, qp + 8);
            const ushort* hrow = hidS + j * 72 + sub * 16;
            uint4 ha = *(const uint4*)hrow;
            uint4 hc = *(const uint4*)(hrow + 8);
            const float* qwp = &qwS[h * 64 + sub * 16];
            float d2 = dot8(ha, qwp) + dot8(hc, qwp + 8);
            float pp = d1 + d2;
            pp += __shfl_xor(pp, 1, 64);
            pp += __shfl_xor(pp, 2, 64);
            pp *= 0.125f;
            float mx = pp;
            mx = fmaxf(mx, __shfl_xor(mx, 4, 64));
            mx = fmaxf(mx, __shfl_xor(mx, 8, 64));
            mx = fmaxf(mx, __shfl_xor(mx, 16, 64));
            mx = fmaxf(mx, __shfl_xor(mx, 32, 64));
            float e = expf(pp - mx);
            float ss = e;
            ss += __shfl_xor(ss, 4, 64);
            ss += __shfl_xor(ss, 8, 64);
            ss += __shfl_xor(ss, 16, 64);
            ss += __shfl_xor(ss, 32, 64);
            float pj = e / ss;
            if (sub == 0) psS[h * 16 + j] = pj;
        }
        __syncthreads();

        // partial + hp
        {
            float o = 0.f, hpv = 0.f;
            #pragma unroll
            for (int j = 0; j < 16; ++j) {
                float p = psS[h * 16 + j];
                int m = nbAll[pt * 16 + j];
                o   += p * b2f(qkvw[(base + m) * 1024 + 512 + t]);
                hpv += p * b2f(hidS[j * 72 + lane]);
            }
            ab[(size_t)bn * 512 + t]       = f2b(o);
            ab[(size_t)bn * 512 + 256 + t] = f2b(hpv);
        }
        __syncthreads();
    }
}

// ---------------------------------------------------------------------------
extern "C" void kernel_launch(void* const* d_in, const int* in_sizes, int n_in,
                              void* d_out, int out_size, void* d_ws, size_t ws_size,
                              hipStream_t stream) {
    const float* xyz    = (const float*)d_in[0];
    const float* feats  = (const float*)d_in[1];
    const float* ln_q_g = (const float*)d_in[2];
    const float* ln_q_b = (const float*)d_in[3];
    const float* Wq     = (const float*)d_in[4];
    const float* bq     = (const float*)d_in[5];
    const float* Wk     = (const float*)d_in[6];
    const float* bk     = (const float*)d_in[7];
    const float* Wv     = (const float*)d_in[8];
    const float* bv     = (const float*)d_in[9];
    const float* W_rel1 = (const float*)d_in[10];
    const float* b_rel1 = (const float*)d_in[11];
    const float* W_rel2 = (const float*)d_in[12];
    const float* b_rel2 = (const float*)d_in[13];
    const float* Wo     = (const float*)d_in[14];
    const float* bo     = (const float*)d_in[15];
    const float* ln_f_g = (const float*)d_in[16];
    const float* ln_f_b = (const float*)d_in[17];
    const float* W_ff1  = (const float*)d_in[18];
    const float* b_ff1  = (const float*)d_in[19];
    const float* W_ff2  = (const float*)d_in[20];
    const float* b_ff2  = (const float*)d_in[21];
    (void)in_sizes; (void)n_in; (void)out_size; (void)ws_size;

    char* ws = (char*)d_ws;
    const size_t MB = 1u << 20;
    int*    idx    = (int*)ws;                        // 1 MB
    ushort* xb     = (ushort*)(ws + 1 * MB);          // 8 MB  (LN out; reused as h)
    ushort* qkvw   = (ushort*)(ws + 9 * MB);          // 32 MB [16384][1024]; feats1 overlays
    ushort* ff1b   = (ushort*)(ws + 41 * MB);         // 32 MB (ff1 out)
    ushort* ab     = (ushort*)(ws + 73 * MB);         // 16 MB [16384][512]
    ushort* BtQKVW = (ushort*)(ws + 89 * MB);         // [1024][256] = 512 KB
    ushort* WoT    = BtQKVW + 262144;                 // 128 KB
    ushort* Wf1T   = WoT + 65536;                     // [1024][256] 512 KB
    ushort* Wf2T   = Wf1T + 262144;                   // [256][1024] 512 KB
    ushort* Wq_bf  = Wf2T + 262144;                   // 128 KB
    ushort* w2bd   = Wq_bf + 65536;                   // 128 KB
    ushort* BtCat  = w2bd + 65536;                    // [256][512] 256 KB
    float*  bqkvw  = (float*)(BtCat + 131072);        // 1024 f32
    float*  boc    = bqkvw + 1024;                    // 256 f32
    float*  feats1 = (float*)(ws + 9 * MB);           // overlays qkvw (dead by then)
    ushort* hb     = xb;                              // overlays xb (dead by then)

    // ---- weight preprocessing ----
    tconv4<<<dim3(8, 8, 4), 256, 0, stream>>>(Wq, Wk, Wv, Wo,
                                              BtQKVW, BtQKVW + 65536, BtQKVW + 131072, WoT);
    tconv<<<dim3(32, 8), 256, 0, stream>>>(W_ff1, Wf1T, 256, 1024);
    tconv<<<dim3(8, 32), 256, 0, stream>>>(W_ff2, Wf2T, 1024, 256);
    prep_mats<<<768, 256, 0, stream>>>(W_rel2, Wq, WoT, w2bd, Wq_bf, BtCat);
    gemm_bt<0, 1, 0><<<dim3(2, 2), 256, 0, stream>>>(w2bd, Wq_bf, nullptr, nullptr,
                                                     BtQKVW + 768 * 256, 256, 256, 256, 256);
    gemm_bt<0, 1, 0><<<dim3(2, 2), 256, 0, stream>>>(WoT, w2bd, nullptr, nullptr,
                                                     BtCat + 256, 256, 256, 256, 512);
    prep_bias<<<5, 256, 0, stream>>>(bq, bk, bv, W_rel2, bo, b_rel2, Wo, bqkvw, boc);

    // ---- main pipeline ----
    knn_kernel<<<MTOT / QPB, 256, 0, stream>>>(xyz, idx);
    ln_kernel<<<MTOT, 256, 0, stream>>>(feats, ln_q_g, ln_q_b, xb);

    // fused q|k|v|qw GEMM: [16384][1024]
    gemm_bt<0, 1, 0><<<dim3(8, 128), 256, 0, stream>>>(xb, BtQKVW, bqkvw, nullptr,
                                                       qkvw, MTOT, 1024, 256, 1024);

    attn_kernel<<<MTOT / PTS, 256, 0, stream>>>(idx, qkvw, xyz, W_rel1, b_rel1, ab);

    // feats1 = [partial|hp] @ BtCat^T + boc + feats   (overlays qkvw)
    gemm_bt<0, 0, 1><<<dim3(2, 128), 256, 0, stream>>>(ab, BtCat, boc, feats, feats1, MTOT, 256, 512, 256);
    ln_kernel<<<MTOT, 256, 0, stream>>>(feats1, ln_f_g, ln_f_b, hb);
    gemm_bt<1, 1, 0><<<dim3(8, 128), 256, 0, stream>>>(hb, Wf1T, b_ff1, nullptr, ff1b, MTOT, 1024, 256, 1024);
    gemm_bt<0, 0, 1><<<dim3(2, 128), 256, 0, stream>>>(ff1b, Wf2T, b_ff2, feats1, (float*)d_out, MTOT, 256, 1024, 256);
}

// Round 13
// 283.724 us; speedup vs baseline: 1.2422x; 1.0166x over previous
//
#include <hip/hip_runtime.h>
#include <hip/hip_bf16.h>
#include <math.h>

#define NB 4
#define NPTS 4096
#define DIM 256
#define KNN 16
#define HID 64
#define FFDIM 1024
#define LN_EPS 1e-5f
#define MTOT (NB * NPTS)
#define KINF 3e38f
#define QPB 8

typedef __attribute__((ext_vector_type(8))) short short8;
typedef __attribute__((ext_vector_type(4))) float f32x4;

__device__ __forceinline__ float gelu_f(float x) {
    return 0.5f * x * (1.0f + erff(x * 0.7071067811865476f));
}
__device__ __forceinline__ float b2f(ushort u) {
    return __uint_as_float(((unsigned)u) << 16);
}
__device__ __forceinline__ ushort f2b(float f) {
    unsigned u = __float_as_uint(f);
    return (ushort)((u + 0x7fffu + ((u >> 16) & 1u)) >> 16);
}
__device__ __forceinline__ void gload16(const void* g, void* l) {
    __builtin_amdgcn_global_load_lds((const __attribute__((address_space(1))) void*)g,
                                     (__attribute__((address_space(3))) void*)l, 16, 0, 0);
}
// dot of 8 bf16 (packed in uint4) with 8 consecutive f32
__device__ __forceinline__ float dot8(uint4 w, const float* q) {
    float s = 0.f;
    s += b2f((ushort)(w.x & 0xffff)) * q[0]; s += b2f((ushort)(w.x >> 16)) * q[1];
    s += b2f((ushort)(w.y & 0xffff)) * q[2]; s += b2f((ushort)(w.y >> 16)) * q[3];
    s += b2f((ushort)(w.z & 0xffff)) * q[4]; s += b2f((ushort)(w.z >> 16)) * q[5];
    s += b2f((ushort)(w.w & 0xffff)) * q[6]; s += b2f((ushort)(w.w >> 16)) * q[7];
    return s;
}

// ---------------------------------------------------------------------------
// KNN v8: wave-autonomous. xyz staged in LDS once (1 barrier); wave w owns
// queries w and w+4 end-to-end: 64 distances/lane (kept in regs) -> lane-min
// -> ONE wave sort-64 of lane-mins -> T = rank-15 (same guarantee proof as
// v7, 64 lane-mins) -> compact from stored regs (bitwise pass-1 values,
// count>=16 guaranteed) -> wave-local lexicographic sort-64 -> write.
// No cross-wave LDS traffic, no redundant sorts, wave-private cnt/cV/cI.
// ---------------------------------------------------------------------------
__global__ __launch_bounds__(256) void knn_kernel(const float* __restrict__ xyz,
                                                  int* __restrict__ idx_out) {
    int blk = blockIdx.x;              // MTOT/QPB = 2048
    int bq0 = blk * QPB;
    int b = bq0 >> 12;
    const float* base = xyz + (size_t)b * NPTS * 3;
    int t = threadIdx.x;
    int lane = t & 63, wv = t >> 6;

    __shared__ float pxS[NPTS];        // 16 KB
    __shared__ float pyS[NPTS];
    __shared__ float pzS[NPTS];
    __shared__ int   cnt[QPB];
    __shared__ float cV[QPB][64];
    __shared__ int   cI[QPB][64];

    if (t < QPB) cnt[t] = 0;
    for (int i = t; i < NPTS; i += 256) {
        pxS[i] = base[i * 3 + 0];
        pyS[i] = base[i * 3 + 1];
        pzS[i] = base[i * 3 + 2];
    }
    __syncthreads();                   // the only barrier

    #pragma unroll 1
    for (int rep = 0; rep < 2; ++rep) {
        int qi = wv + 4 * rep;         // wave-private query slot
        int bn = bq0 + qi;
        int n = bn & (NPTS - 1);
        float qx = pxS[n], qy = pyS[n], qz = pzS[n];
        float sqn = qx * qx + qy * qy + qz * qz;

        float d[64];
        float lm = KINF;
        #pragma unroll
        for (int i = 0; i < 64; ++i) {
            int m = lane + 64 * i;
            float x = pxS[m], y = pyS[m], z = pzS[m];
            float sqm = x * x + y * y + z * z;
            float dot = qx * x + qy * y + qz * z;
            float dd = (sqn + sqm) - 2.0f * dot;
            d[i] = (m == n) ? KINF : dd;
            lm = fminf(lm, d[i]);
        }

        // wave ascending bitonic sort of the 64 lane-mins
        float v = lm;
        #pragma unroll
        for (int k = 2; k <= 64; k <<= 1) {
            #pragma unroll
            for (int j = 32; j > 0; j >>= 1) {
                if (j < k) {
                    float ov = __shfl_xor(v, j, 64);
                    bool keepMin = ((lane & k) == 0) == ((lane & j) == 0);
                    if (keepMin == (ov < v)) v = ov;
                }
            }
        }
        float T = __shfl(v, 15, 64);   // 16th-smallest lane-min

        // compact candidates from stored registers (wave-private cnt)
        #pragma unroll
        for (int i = 0; i < 64; ++i) {
            if (d[i] <= T) {
                int pos = atomicAdd(&cnt[qi], 1);
                if (pos < 64) { cV[qi][pos] = d[i]; cI[qi][pos] = lane + 64 * i; }
            }
        }

        // wave-local lexicographic (d, idx) sort of up to 64 candidates
        int nc = cnt[qi]; nc = nc > 64 ? 64 : nc;
        float v2 = (lane < nc) ? cV[qi][lane] : KINF;
        int   m2 = (lane < nc) ? cI[qi][lane] : 0x7fffffff;
        #pragma unroll
        for (int k = 2; k <= 64; k <<= 1) {
            #pragma unroll
            for (int j = 32; j > 0; j >>= 1) {
                if (j < k) {
                    float ov = __shfl_xor(v2, j, 64);
                    int   om = __shfl_xor(m2, j, 64);
                    bool keepMin = ((lane & k) == 0) == ((lane & j) == 0);
                    bool less = (ov < v2) || (ov == v2 && om < m2);
                    if (keepMin == less) { v2 = ov; m2 = om; }
                }
            }
        }
        if (lane < KNN) idx_out[(size_t)bn * KNN + lane] = m2;
    }
}

// ---------------------------------------------------------------------------
// LayerNorm f32 in -> bf16 out
// ---------------------------------------------------------------------------
__global__ __launch_bounds__(256) void ln_kernel(const float* __restrict__ in,
                                                 const float* __restrict__ g,
                                                 const float* __restrict__ bb,
                                                 ushort* __restrict__ out) {
    int r = blockIdx.x;
    int t = threadIdx.x;
    float v = in[(size_t)r * DIM + t];

    __shared__ float sw[4];
    __shared__ float sw2[4];

    float s = v;
    #pragma unroll
    for (int off = 32; off > 0; off >>= 1) s += __shfl_down(s, off);
    if ((t & 63) == 0) sw[t >> 6] = s;
    __syncthreads();
    float mean = (sw[0] + sw[1] + sw[2] + sw[3]) * (1.0f / DIM);

    float dlt = v - mean;
    float s2 = dlt * dlt;
    #pragma unroll
    for (int off = 32; off > 0; off >>= 1) s2 += __shfl_down(s2, off);
    if ((t & 63) == 0) sw2[t >> 6] = s2;
    __syncthreads();
    float var = (sw2[0] + sw2[1] + sw2[2] + sw2[3]) * (1.0f / DIM);

    out[(size_t)r * DIM + t] = f2b(dlt * rsqrtf(var + LN_EPS) * g[t] + bb[t]);
}

// ---------------------------------------------------------------------------
// Batched transpose-convert (4x 256x256)
// ---------------------------------------------------------------------------
__global__ __launch_bounds__(256) void tconv4(const float* __restrict__ s0,
                                              const float* __restrict__ s1,
                                              const float* __restrict__ s2,
                                              const float* __restrict__ s3,
                                              ushort* __restrict__ d0,
                                              ushort* __restrict__ d1,
                                              ushort* __restrict__ d2,
                                              ushort* __restrict__ d3) {
    const float* in; ushort* out;
    switch (blockIdx.z) {
        case 0: in = s0; out = d0; break;
        case 1: in = s1; out = d1; break;
        case 2: in = s2; out = d2; break;
        default: in = s3; out = d3; break;
    }
    __shared__ float tile[32][33];
    int tx = threadIdx.x & 31, ty = threadIdx.x >> 5;
    int r0 = blockIdx.y * 32, c0 = blockIdx.x * 32;
    #pragma unroll
    for (int k = 0; k < 4; ++k)
        tile[ty + 8 * k][tx] = in[(size_t)(r0 + ty + 8 * k) * 256 + c0 + tx];
    __syncthreads();
    #pragma unroll
    for (int k = 0; k < 4; ++k)
        out[(size_t)(c0 + ty + 8 * k) * 256 + r0 + tx] = f2b(tile[tx][ty + 8 * k]);
}

// generic tconv for FF weights
__global__ __launch_bounds__(256) void tconv(const float* __restrict__ in,
                                             ushort* __restrict__ out, int R, int C) {
    __shared__ float tile[32][33];
    int tx = threadIdx.x & 31, ty = threadIdx.x >> 5;
    int r0 = blockIdx.y * 32, c0 = blockIdx.x * 32;
    #pragma unroll
    for (int k = 0; k < 4; ++k)
        tile[ty + 8 * k][tx] = in[(size_t)(r0 + ty + 8 * k) * C + c0 + tx];
    __syncthreads();
    #pragma unroll
    for (int k = 0; k < 4; ++k)
        out[(size_t)(c0 + ty + 8 * k) * R + r0 + tx] = f2b(tile[tx][ty + 8 * k]);
}

// merged: w2bd rows (0..255) | Wq row-major bf16 (256..511) | catL copy (512..767)
__global__ __launch_bounds__(256) void prep_mats(const float* __restrict__ W2,
                                                 const float* __restrict__ Wq,
                                                 const ushort* __restrict__ WoT,
                                                 ushort* __restrict__ w2bd,
                                                 ushort* __restrict__ Wq_bf,
                                                 ushort* __restrict__ BtCat) {
    int bb = blockIdx.x, t = threadIdx.x;
    if (bb < 256) {
        float v = ((t >> 6) == (bb >> 6)) ? W2[(bb & 63) * 256 + t] : 0.0f;
        w2bd[bb * 256 + t] = f2b(v);
    } else if (bb < 512) {
        int r = bb - 256;
        Wq_bf[r * 256 + t] = f2b(Wq[r * 256 + t]);
    } else {
        int r = bb - 512;
        BtCat[(size_t)r * 512 + t] = WoT[r * 256 + t];
    }
}

// merged biases
__global__ __launch_bounds__(256) void prep_bias(const float* __restrict__ bq,
                                                 const float* __restrict__ bk,
                                                 const float* __restrict__ bv,
                                                 const float* __restrict__ W2,
                                                 const float* __restrict__ bo,
                                                 const float* __restrict__ br2,
                                                 const float* __restrict__ Wo,
                                                 float* __restrict__ bqkvw,
                                                 float* __restrict__ boc) {
    int bb = blockIdx.x, t = threadIdx.x;
    if (bb == 0) bqkvw[t] = bq[t];
    else if (bb == 1) bqkvw[256 + t] = bk[t];
    else if (bb == 2) bqkvw[512 + t] = bv[t];
    else if (bb == 3) {
        int h = t >> 6, i = t & 63;
        float s = 0.f;
        #pragma unroll 8
        for (int dp = 0; dp < 64; ++dp) s += bq[h * 64 + dp] * W2[i * 256 + h * 64 + dp];
        bqkvw[768 + t] = s;
    } else {
        float s = bo[t];
        #pragma unroll 8
        for (int d = 0; d < 256; ++d) s += br2[d] * Wo[d * 256 + t];
        boc[t] = s;
    }
}

// ---------------------------------------------------------------------------
// MFMA bf16 GEMM: C[M][ldc] = act(A[M][K] @ Bt[N][K]^T + bias) (+res)
// ---------------------------------------------------------------------------
template <int ACT, int OUTBF, int RES>
__global__ __launch_bounds__(256) void gemm_bt(
    const ushort* __restrict__ A, const ushort* __restrict__ Bt,
    const float* __restrict__ bias, const float* __restrict__ res,
    void* __restrict__ Cv, int M, int N, int K, int ldc)
{
    __shared__ ushort As[4096];
    __shared__ ushort Bs[4096];
    const int t = threadIdx.x;
    const int wave = t >> 6, lane = t & 63;
    const int m0 = blockIdx.y * 128, n0 = blockIdx.x * 128;
    const int wr = (wave >> 1) * 64, wc = (wave & 1) * 64;

    f32x4 acc[4][4];
    #pragma unroll
    for (int i = 0; i < 4; ++i)
        #pragma unroll
        for (int j = 0; j < 4; ++j) acc[i][j] = {0.f, 0.f, 0.f, 0.f};

    const int rA0 = (wave * 2 + 0) * 16 + (lane >> 2);
    const int rA1 = (wave * 2 + 1) * 16 + (lane >> 2);
    const int u4 = lane & 3;
    const int sw0 = (rA0 + (rA0 >> 2)) & 3;
    const int sw1 = (rA1 + (rA1 >> 2)) & 3;
    char* ldsA0 = (char*)As + (wave * 2 + 0) * 1024 + lane * 16;
    char* ldsA1 = (char*)As + (wave * 2 + 1) * 1024 + lane * 16;
    char* ldsB0 = (char*)Bs + (wave * 2 + 0) * 1024 + lane * 16;
    char* ldsB1 = (char*)Bs + (wave * 2 + 1) * 1024 + lane * 16;
    const size_t aOff0 = (size_t)(m0 + rA0) * K + (size_t)((u4 ^ sw0) * 8);
    const size_t aOff1 = (size_t)(m0 + rA1) * K + (size_t)((u4 ^ sw1) * 8);
    const size_t bOff0 = (size_t)(n0 + rA0) * K + (size_t)((u4 ^ sw0) * 8);
    const size_t bOff1 = (size_t)(n0 + rA1) * K + (size_t)((u4 ^ sw1) * 8);

    const int cl = lane & 15, gq = lane >> 4;

    for (int k0 = 0; k0 < K; k0 += 32) {
        gload16(A + aOff0 + k0, ldsA0);
        gload16(A + aOff1 + k0, ldsA1);
        gload16(Bt + bOff0 + k0, ldsB0);
        gload16(Bt + bOff1 + k0, ldsB1);
        __syncthreads();

        short8 av[4], bv[4];
        #pragma unroll
        for (int mi = 0; mi < 4; ++mi) {
            int row = wr + mi * 16 + cl;
            int s = (row + (row >> 2)) & 3;
            av[mi] = *(const short8*)((const char*)As + row * 64 + ((gq ^ s) << 4));
            int rowb = wc + mi * 16 + cl;
            int sb = (rowb + (rowb >> 2)) & 3;
            bv[mi] = *(const short8*)((const char*)Bs + rowb * 64 + ((gq ^ sb) << 4));
        }
        #pragma unroll
        for (int mi = 0; mi < 4; ++mi)
            #pragma unroll
            for (int ni = 0; ni < 4; ++ni)
                acc[mi][ni] = __builtin_amdgcn_mfma_f32_16x16x32_bf16(av[mi], bv[ni], acc[mi][ni], 0, 0, 0);
        __syncthreads();
    }

    float* Cf = (float*)Cv;
    ushort* Cb = (ushort*)Cv;
    #pragma unroll
    for (int ni = 0; ni < 4; ++ni) {
        int col = n0 + wc + ni * 16 + cl;
        float bvv = bias ? bias[col] : 0.0f;
        #pragma unroll
        for (int mi = 0; mi < 4; ++mi) {
            #pragma unroll
            for (int r = 0; r < 4; ++r) {
                int row = m0 + wr + mi * 16 + gq * 4 + r;
                float v = acc[mi][ni][r] + bvv;
                if (ACT == 1) v = gelu_f(v);
                if (RES) v += res[(size_t)row * N + col];
                if (OUTBF) Cb[(size_t)row * ldc + col] = f2b(v);
                else       Cf[(size_t)row * ldc + col] = v;
            }
        }
    }
}

// ---------------------------------------------------------------------------
// Attention v5 (validated round 12): hid in-kernel, prologue barrier,
// q/k/v/qw from fused qkvw[16384][1024].
// ---------------------------------------------------------------------------
#define PTS 8
__global__ __launch_bounds__(256) void attn_kernel(
    const int* __restrict__ idx,
    const ushort* __restrict__ qkvw,
    const float* __restrict__ xyz,
    const float* __restrict__ W1,
    const float* __restrict__ b1,
    ushort* __restrict__ ab)
{
    __shared__ float qS[256];
    __shared__ float qwS[256];
    __shared__ float psS[64];
    __shared__ uint4 hidS4[16 * 9];   // [16 rows][stride 144B]
    __shared__ int   nbAll[128];
    __shared__ float w1S[256];
    __shared__ float b1S[64];
    ushort* hidS = (ushort*)hidS4;

    const int t = threadIdx.x;
    const int h = t >> 6, lane = t & 63;
    const int bid = blockIdx.x;
    const int blk = ((bid & 7) << 8) | (bid >> 3);   // XCD-contiguous, bijective
    const int bn0 = blk * PTS;
    const int R0 = blk * (PTS * 16);

    if (t < 128) nbAll[t] = idx[R0 + t];
    w1S[t] = W1[t];
    if (t < 64) b1S[t] = b1[t];
    const float* xb3 = xyz + (size_t)(bn0 >> 12) * NPTS * 3;
    __syncthreads();   // nbAll/w1S/b1S read cross-wave below

    for (int pt = 0; pt < PTS; ++pt) {
        const int bn = bn0 + pt;
        const size_t base = (size_t)(bn >> 12) * NPTS;

        qS[t]  = b2f(qkvw[(size_t)bn * 1024 + t]);
        qwS[t] = b2f(qkvw[(size_t)bn * 1024 + 768 + t]);
        // compute hid rows for this point: j = t>>4 (16 rows), 4 dims/thread
        {
            int n = bn & (NPTS - 1);
            float nx = xb3[n * 3 + 0], ny = xb3[n * 3 + 1], nz = xb3[n * 3 + 2];
            int j = t >> 4;
            int i0 = (t & 15) * 4;
            int m = nbAll[pt * 16 + j];
            float dx = xb3[m * 3 + 0] - nx;
            float dy = xb3[m * 3 + 1] - ny;
            float dz = xb3[m * 3 + 2] - nz;
            float nr = sqrtf(dx * dx + dy * dy + dz * dz);
            uint2 hw;
            float a0 = b1S[i0 + 0] + dx * w1S[i0 + 0] + dy * w1S[64 + i0 + 0] + dz * w1S[128 + i0 + 0] + nr * w1S[192 + i0 + 0];
            float a1 = b1S[i0 + 1] + dx * w1S[i0 + 1] + dy * w1S[64 + i0 + 1] + dz * w1S[128 + i0 + 1] + nr * w1S[192 + i0 + 1];
            float a2 = b1S[i0 + 2] + dx * w1S[i0 + 2] + dy * w1S[64 + i0 + 2] + dz * w1S[128 + i0 + 2] + nr * w1S[192 + i0 + 2];
            float a3 = b1S[i0 + 3] + dx * w1S[i0 + 3] + dy * w1S[64 + i0 + 3] + dz * w1S[128 + i0 + 3] + nr * w1S[192 + i0 + 3];
            hw.x = (uint)f2b(gelu_f(a0)) | ((uint)f2b(gelu_f(a1)) << 16);
            hw.y = (uint)f2b(gelu_f(a2)) | ((uint)f2b(gelu_f(a3)) << 16);
            *(uint2*)(hidS + j * 72 + i0) = hw;
        }
        __syncthreads();

        // logits + softmax (wave h = head h; lane = j*4+sub)
        {
            int j = lane >> 2, sub = lane & 3;
            int m = nbAll[pt * 16 + j];
            const ushort* krow = qkvw + (base + m) * 1024 + 256 + h * 64 + sub * 16;
            uint4 ka = *(const uint4*)krow;
            uint4 kc = *(const uint4*)(krow + 8);
            const float* qp = &qS[h * 64 + sub * 16];
            float d1 = dot8(ka, qp) + dot8(kc, qp + 8);
            const ushort* hrow = hidS + j * 72 + sub * 16;
            uint4 ha = *(const uint4*)hrow;
            uint4 hc = *(const uint4*)(hrow + 8);
            const float* qwp = &qwS[h * 64 + sub * 16];
            float d2 = dot8(ha, qwp) + dot8(hc, qwp + 8);
            float pp = d1 + d2;
            pp += __shfl_xor(pp, 1, 64);
            pp += __shfl_xor(pp, 2, 64);
            pp *= 0.125f;
            float mx = pp;
            mx = fmaxf(mx, __shfl_xor(mx, 4, 64));
            mx = fmaxf(mx, __shfl_xor(mx, 8, 64));
            mx = fmaxf(mx, __shfl_xor(mx, 16, 64));
            mx = fmaxf(mx, __shfl_xor(mx, 32, 64));
            float e = expf(pp - mx);
            float ss = e;
            ss += __shfl_xor(ss, 4, 64);
            ss += __shfl_xor(ss, 8, 64);
            ss += __shfl_xor(ss, 16, 64);
            ss += __shfl_xor(ss, 32, 64);
            float pj = e / ss;
            if (sub == 0) psS[h * 16 + j] = pj;
        }
        __syncthreads();

        // partial + hp
        {
            float o = 0.f, hpv = 0.f;
            #pragma unroll
            for (int j = 0; j < 16; ++j) {
                float p = psS[h * 16 + j];
                int m = nbAll[pt * 16 + j];
                o   += p * b2f(qkvw[(base + m) * 1024 + 512 + t]);
                hpv += p * b2f(hidS[j * 72 + lane]);
            }
            ab[(size_t)bn * 512 + t]       = f2b(o);
            ab[(size_t)bn * 512 + 256 + t] = f2b(hpv);
        }
        __syncthreads();
    }
}

// ---------------------------------------------------------------------------
extern "C" void kernel_launch(void* const* d_in, const int* in_sizes, int n_in,
                              void* d_out, int out_size, void* d_ws, size_t ws_size,
                              hipStream_t stream) {
    const float* xyz    = (const float*)d_in[0];
    const float* feats  = (const float*)d_in[1];
    const float* ln_q_g = (const float*)d_in[2];
    const float* ln_q_b = (const float*)d_in[3];
    const float* Wq     = (const float*)d_in[4];
    const float* bq     = (const float*)d_in[5];
    const float* Wk     = (const float*)d_in[6];
    const float* bk     = (const float*)d_in[7];
    const float* Wv     = (const float*)d_in[8];
    const float* bv     = (const float*)d_in[9];
    const float* W_rel1 = (const float*)d_in[10];
    const float* b_rel1 = (const float*)d_in[11];
    const float* W_rel2 = (const float*)d_in[12];
    const float* b_rel2 = (const float*)d_in[13];
    const float* Wo     = (const float*)d_in[14];
    const float* bo     = (const float*)d_in[15];
    const float* ln_f_g = (const float*)d_in[16];
    const float* ln_f_b = (const float*)d_in[17];
    const float* W_ff1  = (const float*)d_in[18];
    const float* b_ff1  = (const float*)d_in[19];
    const float* W_ff2  = (const float*)d_in[20];
    const float* b_ff2  = (const float*)d_in[21];
    (void)in_sizes; (void)n_in; (void)out_size; (void)ws_size;

    char* ws = (char*)d_ws;
    const size_t MB = 1u << 20;
    int*    idx    = (int*)ws;                        // 1 MB
    ushort* xb     = (ushort*)(ws + 1 * MB);          // 8 MB  (LN out; reused as h)
    ushort* qkvw   = (ushort*)(ws + 9 * MB);          // 32 MB [16384][1024]; feats1 overlays
    ushort* ff1b   = (ushort*)(ws + 41 * MB);         // 32 MB (ff1 out)
    ushort* ab     = (ushort*)(ws + 73 * MB);         // 16 MB [16384][512]
    ushort* BtQKVW = (ushort*)(ws + 89 * MB);         // [1024][256] = 512 KB
    ushort* WoT    = BtQKVW + 262144;                 // 128 KB
    ushort* Wf1T   = WoT + 65536;                     // [1024][256] 512 KB
    ushort* Wf2T   = Wf1T + 262144;                   // [256][1024] 512 KB
    ushort* Wq_bf  = Wf2T + 262144;                   // 128 KB
    ushort* w2bd   = Wq_bf + 65536;                   // 128 KB
    ushort* BtCat  = w2bd + 65536;                    // [256][512] 256 KB
    float*  bqkvw  = (float*)(BtCat + 131072);        // 1024 f32
    float*  boc    = bqkvw + 1024;                    // 256 f32
    float*  feats1 = (float*)(ws + 9 * MB);           // overlays qkvw (dead by then)
    ushort* hb     = xb;                              // overlays xb (dead by then)

    // ---- weight preprocessing ----
    tconv4<<<dim3(8, 8, 4), 256, 0, stream>>>(Wq, Wk, Wv, Wo,
                                              BtQKVW, BtQKVW + 65536, BtQKVW + 131072, WoT);
    tconv<<<dim3(32, 8), 256, 0, stream>>>(W_ff1, Wf1T, 256, 1024);
    tconv<<<dim3(8, 32), 256, 0, stream>>>(W_ff2, Wf2T, 1024, 256);
    prep_mats<<<768, 256, 0, stream>>>(W_rel2, Wq, WoT, w2bd, Wq_bf, BtCat);
    gemm_bt<0, 1, 0><<<dim3(2, 2), 256, 0, stream>>>(w2bd, Wq_bf, nullptr, nullptr,
                                                     BtQKVW + 768 * 256, 256, 256, 256, 256);
    gemm_bt<0, 1, 0><<<dim3(2, 2), 256, 0, stream>>>(WoT, w2bd, nullptr, nullptr,
                                                     BtCat + 256, 256, 256, 256, 512);
    prep_bias<<<5, 256, 0, stream>>>(bq, bk, bv, W_rel2, bo, b_rel2, Wo, bqkvw, boc);

    // ---- main pipeline ----
    knn_kernel<<<MTOT / QPB, 256, 0, stream>>>(xyz, idx);
    ln_kernel<<<MTOT, 256, 0, stream>>>(feats, ln_q_g, ln_q_b, xb);

    // fused q|k|v|qw GEMM: [16384][1024]
    gemm_bt<0, 1, 0><<<dim3(8, 128), 256, 0, stream>>>(xb, BtQKVW, bqkvw, nullptr,
                                                       qkvw, MTOT, 1024, 256, 1024);

    attn_kernel<<<MTOT / PTS, 256, 0, stream>>>(idx, qkvw, xyz, W_rel1, b_rel1, ab);

    // feats1 = [partial|hp] @ BtCat^T + boc + feats   (overlays qkvw)
    gemm_bt<0, 0, 1><<<dim3(2, 128), 256, 0, stream>>>(ab, BtCat, boc, feats, feats1, MTOT, 256, 512, 256);
    ln_kernel<<<MTOT, 256, 0, stream>>>(feats1, ln_f_g, ln_f_b, hb);
    gemm_bt<1, 1, 0><<<dim3(8, 128), 256, 0, stream>>>(hb, Wf1T, b_ff1, nullptr, ff1b, MTOT, 1024, 256, 1024);
    gemm_bt<0, 0, 1><<<dim3(2, 128), 256, 0, stream>>>(ff1b, Wf2T, b_ff2, feats1, (float*)d_out, MTOT, 256, 1024, 256);
}